// Round 1
// baseline (1348.681 us; speedup 1.0000x reference)
//
#include <hip/hip_runtime.h>

// Problem constants
static constexpr int NB = 16;     // batches
static constexpr int NP = 2048;   // points per batch
static constexpr int NC = 128;    // channels
#define ALPHA_F ((float)(8.0/9.0))
#define OMA_F   ((float)(1.0 - 8.0/9.0))

// ---------------------------------------------------------------------------
// KNN: for each point, find 8 nearest (incl. self at slot 0), emit 7 neighbors
// ---------------------------------------------------------------------------
__global__ __launch_bounds__(256) void knn_kernel(const float* __restrict__ xyz,
                                                  int* __restrict__ nbr) {
    __shared__ float sx[NP], sy[NP], sz[NP], sq[NP];
    int b = blockIdx.y;
    const float* X = xyz + (size_t)b * 3 * NP;
    for (int m = threadIdx.x; m < NP; m += 256) {
        float x = X[m], y = X[NP + m], z = X[2 * NP + m];
        sx[m] = x; sy[m] = y; sz[m] = z;
        sq[m] = x * x + y * y + z * z;
    }
    __syncthreads();
    int n = blockIdx.x * 256 + threadIdx.x;
    float xi = sx[n], yi = sy[n], zi = sz[n], qi = sq[n];
    float bd[8]; int bi[8];
#pragma unroll
    for (int t = 0; t < 8; ++t) { bd[t] = 3.4e38f; bi[t] = 0; }
    for (int j = 0; j < NP; ++j) {
        float inner = xi * sx[j] + yi * sy[j] + zi * sz[j];
        float d = qi + sq[j] - 2.0f * inner;
        if (d < bd[7]) {           // strict < : ties keep smaller (earlier) index
            bd[7] = d; bi[7] = j;
#pragma unroll
            for (int t = 6; t >= 0; --t) {
                if (bd[t + 1] < bd[t]) {
                    float td = bd[t]; bd[t] = bd[t + 1]; bd[t + 1] = td;
                    int ti = bi[t]; bi[t] = bi[t + 1]; bi[t + 1] = ti;
                }
            }
        }
    }
    int row = b * NP + n;
#pragma unroll
    for (int t = 0; t < 7; ++t) nbr[row * 7 + t] = bi[t + 1];
}

// ---------------------------------------------------------------------------
// Generic batched transpose of last two dims: in (B,R,S) -> out (B,S,R)
// grid (S/32, R/32, B), block (32,8)
// ---------------------------------------------------------------------------
__global__ __launch_bounds__(256) void transpose_kernel(const float* __restrict__ in,
                                                        float* __restrict__ out,
                                                        int R, int S) {
    __shared__ float t[32][33];
    int b = blockIdx.z;
    int s0 = blockIdx.x * 32, r0 = blockIdx.y * 32;
    const float* I = in + (size_t)b * R * S;
    float* O = out + (size_t)b * R * S;
#pragma unroll
    for (int i = 0; i < 4; ++i) {
        int r = r0 + threadIdx.y + i * 8;
        t[threadIdx.y + i * 8][threadIdx.x] = I[(size_t)r * S + s0 + threadIdx.x];
    }
    __syncthreads();
#pragma unroll
    for (int i = 0; i < 4; ++i) {
        int s = s0 + threadIdx.y + i * 8;
        O[(size_t)s * R + r0 + threadIdx.x] = t[threadIdx.x][threadIdx.y + i * 8];
    }
}

// ---------------------------------------------------------------------------
// Dual GEMM: Y1 = relu(P) @ Wc^T ; Y2 = P @ Wg^T
// P: (32768,128) row-major. Wc/Wg: (128,128) (out_dim, in_dim).
// Block: 256 thr, tile 64 rows x 128 cols, thread = 4 rows x 8 strided cols.
// ---------------------------------------------------------------------------
__global__ __launch_bounds__(256) void gemm2_kernel(const float* __restrict__ P,
                                                    const float* __restrict__ Wc,
                                                    const float* __restrict__ Wg,
                                                    float* __restrict__ Y1,
                                                    float* __restrict__ Y2) {
    __shared__ float Alds[64][132];     // stride 132: 2-way bank alias only
    __shared__ float Wclds[128][36];    // [out_dim][k-chunk], stride 36
    __shared__ float Wglds[128][36];
    int tid = threadIdx.x;
    int tx = tid & 15, ty = tid >> 4;
    size_t rowBase = (size_t)blockIdx.x * 64;
    const float* Pblk = P + rowBase * NC;

    // Stage A tile (64 x 128), fully coalesced
    {
        const float4* src = (const float4*)Pblk;
#pragma unroll
        for (int m = 0; m < 8; ++m) {
            int f = tid + 256 * m;
            int r = f >> 5, c4 = (f & 31) * 4;
            *((float4*)&Alds[r][c4]) = src[f];
        }
    }

    float accC[4][8], accG[4][8];
#pragma unroll
    for (int i = 0; i < 4; ++i)
#pragma unroll
        for (int j = 0; j < 8; ++j) { accC[i][j] = 0.f; accG[i][j] = 0.f; }

    for (int kc = 0; kc < 4; ++kc) {
        __syncthreads();   // A ready (kc=0) / previous W chunk consumed
        {
            int d = tid >> 1, h = (tid & 1) * 16;
            const float4* sc = (const float4*)(Wc + d * NC + kc * 32 + h);
            const float4* sg = (const float4*)(Wg + d * NC + kc * 32 + h);
#pragma unroll
            for (int m = 0; m < 4; ++m) {
                *((float4*)&Wclds[d][h + 4 * m]) = sc[m];
                *((float4*)&Wglds[d][h + 4 * m]) = sg[m];
            }
        }
        __syncthreads();
#pragma unroll
        for (int kk4 = 0; kk4 < 8; ++kk4) {
            int k = kc * 32 + kk4 * 4;
            float4 a[4], ar[4];
#pragma unroll
            for (int i = 0; i < 4; ++i) {
                a[i] = *((const float4*)&Alds[ty * 4 + i][k]);
                ar[i].x = fmaxf(a[i].x, 0.f);
                ar[i].y = fmaxf(a[i].y, 0.f);
                ar[i].z = fmaxf(a[i].z, 0.f);
                ar[i].w = fmaxf(a[i].w, 0.f);
            }
#pragma unroll
            for (int j = 0; j < 8; ++j) {
                int cc = tx + 16 * j;
                float4 wc = *((const float4*)&Wclds[cc][kk4 * 4]);
                float4 wg = *((const float4*)&Wglds[cc][kk4 * 4]);
#pragma unroll
                for (int i = 0; i < 4; ++i) {
                    accC[i][j] += ar[i].x * wc.x + ar[i].y * wc.y + ar[i].z * wc.z + ar[i].w * wc.w;
                    accG[i][j] += a[i].x * wg.x + a[i].y * wg.y + a[i].z * wg.z + a[i].w * wg.w;
                }
            }
        }
    }
    // Store (strided cols -> scalar stores; 4x 64B segments per inst)
#pragma unroll
    for (int i = 0; i < 4; ++i) {
        size_t row = rowBase + ty * 4 + i;
#pragma unroll
        for (int j = 0; j < 8; ++j) {
            Y1[row * NC + tx + 16 * j] = accC[i][j];
            Y2[row * NC + tx + 16 * j] = accG[i][j];
        }
    }
}

// ---------------------------------------------------------------------------
// Aggregate + residual: Pout = P + ALPHA*Y1 + (1-ALPHA)*( (Y2[n]+sum_nbr)/8 )
// 32 threads (float4 each) per row; 8 rows per block.
// ---------------------------------------------------------------------------
__global__ __launch_bounds__(256) void agg_kernel(const float* __restrict__ P,
                                                  const float* __restrict__ Y1,
                                                  const float* __restrict__ Y2,
                                                  const int* __restrict__ nbr,
                                                  float* __restrict__ Pout) {
    int tid = threadIdx.x;
    int lane = tid & 31, rl = tid >> 5;
    size_t row = (size_t)blockIdx.x * 8 + rl;
    int b = (int)(row >> 11);
    const int* nb = nbr + row * 7;
    size_t off = row * NC + lane * 4;
    float4 ys = *((const float4*)(Y2 + off));
    size_t bbase = (size_t)b * NP * NC;
#pragma unroll
    for (int t = 0; t < 7; ++t) {
        int j = nb[t];
        float4 v = *((const float4*)(Y2 + bbase + (size_t)j * NC + lane * 4));
        ys.x += v.x; ys.y += v.y; ys.z += v.z; ys.w += v.w;
    }
    float4 p = *((const float4*)(P + off));
    float4 y1 = *((const float4*)(Y1 + off));
    float4 o;
    o.x = OMA_F * (0.125f * ys.x) + ALPHA_F * y1.x + p.x;
    o.y = OMA_F * (0.125f * ys.y) + ALPHA_F * y1.y + p.y;
    o.z = OMA_F * (0.125f * ys.z) + ALPHA_F * y1.z + p.z;
    o.w = OMA_F * (0.125f * ys.w) + ALPHA_F * y1.w + p.w;
    *((float4*)(Pout + off)) = o;
}

// ---------------------------------------------------------------------------
// Final small GEMMs: U1 = P @ Wuc^T (6), U2 = P @ Wug^T (6); U row = [U1|U2]
// One thread per row.
// ---------------------------------------------------------------------------
__global__ __launch_bounds__(256) void final_gemm_kernel(const float* __restrict__ P,
                                                         const float* __restrict__ Wuc,
                                                         const float* __restrict__ Wug,
                                                         float* __restrict__ U) {
    __shared__ float s1[6 * NC], s2[6 * NC];
    for (int m = threadIdx.x; m < 6 * NC; m += 256) { s1[m] = Wuc[m]; s2[m] = Wug[m]; }
    __syncthreads();
    size_t row = (size_t)blockIdx.x * 256 + threadIdx.x;
    const float4* prow = (const float4*)(P + row * NC);
    float a1[6] = {0, 0, 0, 0, 0, 0}, a2[6] = {0, 0, 0, 0, 0, 0};
    for (int c4 = 0; c4 < NC / 4; ++c4) {
        float4 p = prow[c4];
#pragma unroll
        for (int o = 0; o < 6; ++o) {
            float4 w1 = *((const float4*)&s1[o * NC + c4 * 4]);
            float4 w2 = *((const float4*)&s2[o * NC + c4 * 4]);
            a1[o] += p.x * w1.x + p.y * w1.y + p.z * w1.z + p.w * w1.w;
            a2[o] += p.x * w2.x + p.y * w2.y + p.z * w2.z + p.w * w2.w;
        }
    }
#pragma unroll
    for (int o = 0; o < 6; ++o) {
        U[row * 12 + o] = a1[o];
        U[row * 12 + 6 + o] = a2[o];
    }
}

// ---------------------------------------------------------------------------
// Final output: new_xyz[b][c][s*N+n] = ALPHA*U1[o]+ (1-ALPHA)*(aggU2[o]/8) + xyz[b][c][n]
// (o = 2c+s). One thread per (b,n).
// ---------------------------------------------------------------------------
__global__ __launch_bounds__(256) void final_out_kernel(const float* __restrict__ U,
                                                        const int* __restrict__ nbr,
                                                        const float* __restrict__ xyz,
                                                        float* __restrict__ out) {
    size_t row = (size_t)blockIdx.x * 256 + threadIdx.x;
    int b = (int)(row >> 11), n = (int)(row & 2047);
    const int* nb = nbr + row * 7;
    float u1[6], u2[6];
#pragma unroll
    for (int o = 0; o < 6; ++o) { u1[o] = U[row * 12 + o]; u2[o] = U[row * 12 + 6 + o]; }
#pragma unroll
    for (int t = 0; t < 7; ++t) {
        int j = nb[t];
        const float* Uj = U + ((size_t)b * NP + j) * 12 + 6;
#pragma unroll
        for (int o = 0; o < 6; ++o) u2[o] += Uj[o];
    }
#pragma unroll
    for (int c = 0; c < 3; ++c)
#pragma unroll
        for (int s = 0; s < 2; ++s) {
            int o = c * 2 + s;
            float val = ALPHA_F * u1[o] + OMA_F * (0.125f * u2[o])
                      + xyz[(size_t)b * 3 * NP + (size_t)c * NP + n];
            out[(size_t)b * 3 * 2 * NP + (size_t)c * 2 * NP + (size_t)s * NP + n] = val;
        }
}

// ---------------------------------------------------------------------------
extern "C" void kernel_launch(void* const* d_in, const int* in_sizes, int n_in,
                              void* d_out, int out_size, void* d_ws, size_t ws_size,
                              hipStream_t stream) {
    const float* xyz    = (const float*)d_in[0];  // (16,3,2048)
    const float* points = (const float*)d_in[1];  // (16,128,2048)
    const float* Wc     = (const float*)d_in[2];  // (4,128,128)
    const float* Wg     = (const float*)d_in[3];  // (4,128,128)
    const float* Wuc    = (const float*)d_in[4];  // (6,128)
    const float* Wug    = (const float*)d_in[5];  // (6,128)
    float* out = (float*)d_out;

    char* ws = (char*)d_ws;
    size_t o = 0;
    int* nbr = (int*)(ws + o);      o += (size_t)NB * NP * 7 * 4;      // 917504
    float* P0 = (float*)(ws + o);   o += (size_t)NB * NP * NC * 4;     // 16 MB
    float* P1 = (float*)(ws + o);   o += (size_t)NB * NP * NC * 4;
    float* Y1 = (float*)(ws + o);   o += (size_t)NB * NP * NC * 4;
    float* Y2 = (float*)(ws + o);   o += (size_t)NB * NP * NC * 4;
    float* U  = (float*)(ws + o);   o += (size_t)NB * NP * 12 * 4;

    // 1) points (B,C,N) -> P0 (B,N,C)
    transpose_kernel<<<dim3(NP / 32, NC / 32, NB), dim3(32, 8), 0, stream>>>(points, P0, NC, NP);
    // 2) KNN
    knn_kernel<<<dim3(NP / 256, NB), 256, 0, stream>>>(xyz, nbr);
    // 3) 4 GCN blocks (ping-pong P0<->P1)
    float* Pin = P0; float* Pout = P1;
    for (int i = 0; i < 4; ++i) {
        gemm2_kernel<<<dim3(NB * NP / 64), 256, 0, stream>>>(
            Pin, Wc + (size_t)i * NC * NC, Wg + (size_t)i * NC * NC, Y1, Y2);
        agg_kernel<<<dim3(NB * NP / 8), 256, 0, stream>>>(Pin, Y1, Y2, nbr, Pout);
        float* tmp = Pin; Pin = Pout; Pout = tmp;
    }
    // Pin now holds final pts (B,N,C)
    // 4) final small GEMMs
    final_gemm_kernel<<<dim3(NB * NP / 256), 256, 0, stream>>>(Pin, Wuc, Wug, U);
    // 5) new_xyz
    final_out_kernel<<<dim3(NB * NP / 256), 256, 0, stream>>>(U, nbr, xyz, out);
    // 6) pts (B,N,C) -> out2 (B,C,N)
    transpose_kernel<<<dim3(NC / 32, NP / 32, NB), dim3(32, 8), 0, stream>>>(
        Pin, out + (size_t)NB * 3 * 2 * NP, NP, NC);
}

// Round 2
// 583.102 us; speedup vs baseline: 2.3129x; 2.3129x over previous
//
#include <hip/hip_runtime.h>

// Problem constants
static constexpr int NB = 16;     // batches
static constexpr int NP = 2048;   // points per batch
static constexpr int NC = 128;    // channels
#define ALPHA_F ((float)(8.0/9.0))
#define OMA_F   ((float)(1.0 - 8.0/9.0))

// ---------------------------------------------------------------------------
// KNN v2: 4 threads per point, each scans an interleaved quarter (j = 4*jj+q),
// keeps a private top-8, then a stable LDS merge produces the final top-8.
// Points packed as float4 {x, y, z, |p|^2} -> one ds_read_b128 per candidate.
// Grid: (NP/64, NB) = 512 blocks of 256 threads (64 points per block).
// ---------------------------------------------------------------------------
__global__ __launch_bounds__(256) void knn_kernel(const float* __restrict__ xyz,
                                                  int* __restrict__ nbr) {
    __shared__ float4 sp[NP];            // 32 KB
    __shared__ float2 mrg[64][33];       // 16.9 KB, padded: no bank conflicts
    int b = blockIdx.y;
    const float* X = xyz + (size_t)b * 3 * NP;
    for (int m = threadIdx.x; m < NP; m += 256) {
        float x = X[m], y = X[NP + m], z = X[2 * NP + m];
        sp[m] = make_float4(x, y, z, x * x + y * y + z * z);
    }
    __syncthreads();

    int tid = threadIdx.x;
    int p = tid >> 2;                    // local point 0..63
    int q = tid & 3;                     // quarter 0..3
    int base = blockIdx.x * 64;
    int n = base + p;
    float4 me = sp[n];
    float xi = me.x, yi = me.y, zi = me.z, qi = me.w;

    float bd[8]; int bi[8];
#pragma unroll
    for (int t = 0; t < 8; ++t) { bd[t] = 3.4e38f; bi[t] = 0; }

#pragma unroll 4
    for (int jj = 0; jj < NP / 4; ++jj) {
        int j = 4 * jj + q;
        float4 c = sp[j];
        float inner = xi * c.x + yi * c.y + zi * c.z;
        float d = qi + c.w - 2.0f * inner;
        if (d < bd[7]) {
            bd[7] = d; bi[7] = j;
#pragma unroll
            for (int t = 6; t >= 0; --t) {
                if (bd[t + 1] < bd[t]) {
                    float td = bd[t]; bd[t] = bd[t + 1]; bd[t + 1] = td;
                    int ti = bi[t]; bi[t] = bi[t + 1]; bi[t + 1] = ti;
                }
            }
        }
    }
#pragma unroll
    for (int t = 0; t < 8; ++t)
        mrg[p][q * 8 + t] = make_float2(bd[t], __int_as_float(bi[t]));
    __syncthreads();

    if (tid < 64) {
        float fd[8]; int fi[8];
#pragma unroll
        for (int t = 0; t < 8; ++t) { fd[t] = 3.4e38f; fi[t] = 0; }
#pragma unroll 4
        for (int c = 0; c < 32; ++c) {
            float2 v = mrg[tid][c];
            float d = v.x;
            if (d < fd[7]) {
                fd[7] = d; fi[7] = __float_as_int(v.y);
#pragma unroll
                for (int t = 6; t >= 0; --t) {
                    if (fd[t + 1] < fd[t]) {
                        float td = fd[t]; fd[t] = fd[t + 1]; fd[t + 1] = td;
                        int ti = fi[t]; fi[t] = fi[t + 1]; fi[t + 1] = ti;
                    }
                }
            }
        }
        int row = b * NP + base + tid;
#pragma unroll
        for (int t = 0; t < 7; ++t) nbr[row * 7 + t] = fi[t + 1];
    }
}

// ---------------------------------------------------------------------------
// Generic batched transpose of last two dims: in (B,R,S) -> out (B,S,R)
// grid (S/32, R/32, B), block (32,8)
// ---------------------------------------------------------------------------
__global__ __launch_bounds__(256) void transpose_kernel(const float* __restrict__ in,
                                                        float* __restrict__ out,
                                                        int R, int S) {
    __shared__ float t[32][33];
    int b = blockIdx.z;
    int s0 = blockIdx.x * 32, r0 = blockIdx.y * 32;
    const float* I = in + (size_t)b * R * S;
    float* O = out + (size_t)b * R * S;
#pragma unroll
    for (int i = 0; i < 4; ++i) {
        int r = r0 + threadIdx.y + i * 8;
        t[threadIdx.y + i * 8][threadIdx.x] = I[(size_t)r * S + s0 + threadIdx.x];
    }
    __syncthreads();
#pragma unroll
    for (int i = 0; i < 4; ++i) {
        int s = s0 + threadIdx.y + i * 8;
        O[(size_t)s * R + r0 + threadIdx.x] = t[threadIdx.x][threadIdx.y + i * 8];
    }
}

// ---------------------------------------------------------------------------
// Dual GEMM: Y1 = relu(P) @ Wc^T ; Y2 = P @ Wg^T
// P: (32768,128) row-major. Wc/Wg: (128,128) (out_dim, in_dim).
// Block: 256 thr, tile 64 rows x 128 cols, thread = 4 rows x 8 strided cols.
// kc/kk4 loops pinned to unroll 1: the kk4 body already has 256 independent
// FMAs of ILP; unrolling only inflates VGPR pressure (round-1 spill: VGPR=256,
// 664 MB of scratch traffic).
// ---------------------------------------------------------------------------
__global__ __launch_bounds__(256) void gemm2_kernel(const float* __restrict__ P,
                                                    const float* __restrict__ Wc,
                                                    const float* __restrict__ Wg,
                                                    float* __restrict__ Y1,
                                                    float* __restrict__ Y2) {
    __shared__ float Alds[64][132];     // stride 132: 2-way bank alias only
    __shared__ float Wclds[128][36];    // [out_dim][k-chunk], stride 36
    __shared__ float Wglds[128][36];
    int tid = threadIdx.x;
    int tx = tid & 15, ty = tid >> 4;
    size_t rowBase = (size_t)blockIdx.x * 64;
    const float* Pblk = P + rowBase * NC;

    // Stage A tile (64 x 128), fully coalesced
    {
        const float4* src = (const float4*)Pblk;
#pragma unroll
        for (int m = 0; m < 8; ++m) {
            int f = tid + 256 * m;
            int r = f >> 5, c4 = (f & 31) * 4;
            *((float4*)&Alds[r][c4]) = src[f];
        }
    }

    float accC[4][8], accG[4][8];
#pragma unroll
    for (int i = 0; i < 4; ++i)
#pragma unroll
        for (int j = 0; j < 8; ++j) { accC[i][j] = 0.f; accG[i][j] = 0.f; }

#pragma unroll 1
    for (int kc = 0; kc < 4; ++kc) {
        __syncthreads();   // A ready (kc=0) / previous W chunk consumed
        {
            int d = tid >> 1, h = (tid & 1) * 16;
            const float4* sc = (const float4*)(Wc + d * NC + kc * 32 + h);
            const float4* sg = (const float4*)(Wg + d * NC + kc * 32 + h);
#pragma unroll
            for (int m = 0; m < 4; ++m) {
                *((float4*)&Wclds[d][h + 4 * m]) = sc[m];
                *((float4*)&Wglds[d][h + 4 * m]) = sg[m];
            }
        }
        __syncthreads();
#pragma unroll 1
        for (int kk4 = 0; kk4 < 8; ++kk4) {
            int k = kk4 * 4;
            float4 a[4], ar[4];
#pragma unroll
            for (int i = 0; i < 4; ++i) {
                a[i] = *((const float4*)&Alds[ty * 4 + i][kc * 32 + k]);
                ar[i].x = fmaxf(a[i].x, 0.f);
                ar[i].y = fmaxf(a[i].y, 0.f);
                ar[i].z = fmaxf(a[i].z, 0.f);
                ar[i].w = fmaxf(a[i].w, 0.f);
            }
#pragma unroll
            for (int j = 0; j < 8; ++j) {
                int cc = tx + 16 * j;
                float4 wc = *((const float4*)&Wclds[cc][k]);
                float4 wg = *((const float4*)&Wglds[cc][k]);
#pragma unroll
                for (int i = 0; i < 4; ++i) {
                    accC[i][j] += ar[i].x * wc.x + ar[i].y * wc.y + ar[i].z * wc.z + ar[i].w * wc.w;
                    accG[i][j] += a[i].x * wg.x + a[i].y * wg.y + a[i].z * wg.z + a[i].w * wg.w;
                }
            }
        }
    }
    // Store (strided cols; each 16-lane cluster writes a contiguous 64B run)
#pragma unroll
    for (int i = 0; i < 4; ++i) {
        size_t row = rowBase + ty * 4 + i;
#pragma unroll
        for (int j = 0; j < 8; ++j) {
            Y1[row * NC + tx + 16 * j] = accC[i][j];
            Y2[row * NC + tx + 16 * j] = accG[i][j];
        }
    }
}

// ---------------------------------------------------------------------------
// Aggregate + residual: Pout = P + ALPHA*Y1 + (1-ALPHA)*( (Y2[n]+sum_nbr)/8 )
// 32 threads (float4 each) per row; 8 rows per block.
// ---------------------------------------------------------------------------
__global__ __launch_bounds__(256) void agg_kernel(const float* __restrict__ P,
                                                  const float* __restrict__ Y1,
                                                  const float* __restrict__ Y2,
                                                  const int* __restrict__ nbr,
                                                  float* __restrict__ Pout) {
    int tid = threadIdx.x;
    int lane = tid & 31, rl = tid >> 5;
    size_t row = (size_t)blockIdx.x * 8 + rl;
    int b = (int)(row >> 11);
    const int* nb = nbr + row * 7;
    size_t off = row * NC + lane * 4;
    float4 ys = *((const float4*)(Y2 + off));
    size_t bbase = (size_t)b * NP * NC;
#pragma unroll
    for (int t = 0; t < 7; ++t) {
        int j = nb[t];
        float4 v = *((const float4*)(Y2 + bbase + (size_t)j * NC + lane * 4));
        ys.x += v.x; ys.y += v.y; ys.z += v.z; ys.w += v.w;
    }
    float4 p = *((const float4*)(P + off));
    float4 y1 = *((const float4*)(Y1 + off));
    float4 o;
    o.x = OMA_F * (0.125f * ys.x) + ALPHA_F * y1.x + p.x;
    o.y = OMA_F * (0.125f * ys.y) + ALPHA_F * y1.y + p.y;
    o.z = OMA_F * (0.125f * ys.z) + ALPHA_F * y1.z + p.z;
    o.w = OMA_F * (0.125f * ys.w) + ALPHA_F * y1.w + p.w;
    *((float4*)(Pout + off)) = o;
}

// ---------------------------------------------------------------------------
// Final small GEMMs: U1 = P @ Wuc^T (6), U2 = P @ Wug^T (6); U row = [U1|U2]
// One thread per row.
// ---------------------------------------------------------------------------
__global__ __launch_bounds__(256) void final_gemm_kernel(const float* __restrict__ P,
                                                         const float* __restrict__ Wuc,
                                                         const float* __restrict__ Wug,
                                                         float* __restrict__ U) {
    __shared__ float s1[6 * NC], s2[6 * NC];
    for (int m = threadIdx.x; m < 6 * NC; m += 256) { s1[m] = Wuc[m]; s2[m] = Wug[m]; }
    __syncthreads();
    size_t row = (size_t)blockIdx.x * 256 + threadIdx.x;
    const float4* prow = (const float4*)(P + row * NC);
    float a1[6] = {0, 0, 0, 0, 0, 0}, a2[6] = {0, 0, 0, 0, 0, 0};
#pragma unroll 4
    for (int c4 = 0; c4 < NC / 4; ++c4) {
        float4 p = prow[c4];
#pragma unroll
        for (int o = 0; o < 6; ++o) {
            float4 w1 = *((const float4*)&s1[o * NC + c4 * 4]);
            float4 w2 = *((const float4*)&s2[o * NC + c4 * 4]);
            a1[o] += p.x * w1.x + p.y * w1.y + p.z * w1.z + p.w * w1.w;
            a2[o] += p.x * w2.x + p.y * w2.y + p.z * w2.z + p.w * w2.w;
        }
    }
#pragma unroll
    for (int o = 0; o < 6; ++o) {
        U[row * 12 + o] = a1[o];
        U[row * 12 + 6 + o] = a2[o];
    }
}

// ---------------------------------------------------------------------------
// Final output: new_xyz[b][c][s*N+n] = ALPHA*U1[o]+ (1-ALPHA)*(aggU2[o]/8) + xyz[b][c][n]
// (o = 2c+s). One thread per (b,n).
// ---------------------------------------------------------------------------
__global__ __launch_bounds__(256) void final_out_kernel(const float* __restrict__ U,
                                                        const int* __restrict__ nbr,
                                                        const float* __restrict__ xyz,
                                                        float* __restrict__ out) {
    size_t row = (size_t)blockIdx.x * 256 + threadIdx.x;
    int b = (int)(row >> 11), n = (int)(row & 2047);
    const int* nb = nbr + row * 7;
    float u1[6], u2[6];
#pragma unroll
    for (int o = 0; o < 6; ++o) { u1[o] = U[row * 12 + o]; u2[o] = U[row * 12 + 6 + o]; }
#pragma unroll
    for (int t = 0; t < 7; ++t) {
        int j = nb[t];
        const float* Uj = U + ((size_t)b * NP + j) * 12 + 6;
#pragma unroll
        for (int o = 0; o < 6; ++o) u2[o] += Uj[o];
    }
#pragma unroll
    for (int c = 0; c < 3; ++c)
#pragma unroll
        for (int s = 0; s < 2; ++s) {
            int o = c * 2 + s;
            float val = ALPHA_F * u1[o] + OMA_F * (0.125f * u2[o])
                      + xyz[(size_t)b * 3 * NP + (size_t)c * NP + n];
            out[(size_t)b * 3 * 2 * NP + (size_t)c * 2 * NP + (size_t)s * NP + n] = val;
        }
}

// ---------------------------------------------------------------------------
extern "C" void kernel_launch(void* const* d_in, const int* in_sizes, int n_in,
                              void* d_out, int out_size, void* d_ws, size_t ws_size,
                              hipStream_t stream) {
    const float* xyz    = (const float*)d_in[0];  // (16,3,2048)
    const float* points = (const float*)d_in[1];  // (16,128,2048)
    const float* Wc     = (const float*)d_in[2];  // (4,128,128)
    const float* Wg     = (const float*)d_in[3];  // (4,128,128)
    const float* Wuc    = (const float*)d_in[4];  // (6,128)
    const float* Wug    = (const float*)d_in[5];  // (6,128)
    float* out = (float*)d_out;

    char* ws = (char*)d_ws;
    size_t o = 0;
    int* nbr = (int*)(ws + o);      o += (size_t)NB * NP * 7 * 4;      // 917504
    float* P0 = (float*)(ws + o);   o += (size_t)NB * NP * NC * 4;     // 16 MB
    float* P1 = (float*)(ws + o);   o += (size_t)NB * NP * NC * 4;
    float* Y1 = (float*)(ws + o);   o += (size_t)NB * NP * NC * 4;
    float* Y2 = (float*)(ws + o);   o += (size_t)NB * NP * NC * 4;
    float* U  = (float*)(ws + o);   o += (size_t)NB * NP * 12 * 4;

    // 1) points (B,C,N) -> P0 (B,N,C)
    transpose_kernel<<<dim3(NP / 32, NC / 32, NB), dim3(32, 8), 0, stream>>>(points, P0, NC, NP);
    // 2) KNN
    knn_kernel<<<dim3(NP / 64, NB), 256, 0, stream>>>(xyz, nbr);
    // 3) 4 GCN blocks (ping-pong P0<->P1)
    float* Pin = P0; float* Pout = P1;
    for (int i = 0; i < 4; ++i) {
        gemm2_kernel<<<dim3(NB * NP / 64), 256, 0, stream>>>(
            Pin, Wc + (size_t)i * NC * NC, Wg + (size_t)i * NC * NC, Y1, Y2);
        agg_kernel<<<dim3(NB * NP / 8), 256, 0, stream>>>(Pin, Y1, Y2, nbr, Pout);
        float* tmp = Pin; Pin = Pout; Pout = tmp;
    }
    // Pin now holds final pts (B,N,C)
    // 4) final small GEMMs
    final_gemm_kernel<<<dim3(NB * NP / 256), 256, 0, stream>>>(Pin, Wuc, Wug, U);
    // 5) new_xyz
    final_out_kernel<<<dim3(NB * NP / 256), 256, 0, stream>>>(U, nbr, xyz, out);
    // 6) pts (B,N,C) -> out2 (B,C,N)
    transpose_kernel<<<dim3(NC / 32, NP / 32, NB), dim3(32, 8), 0, stream>>>(
        Pin, out + (size_t)NB * 3 * 2 * NP, NP, NC);
}

// Round 3
// 458.645 us; speedup vs baseline: 2.9406x; 1.2714x over previous
//
#include <hip/hip_runtime.h>

// Problem constants
static constexpr int NB = 16;     // batches
static constexpr int NP = 2048;   // points per batch
static constexpr int NC = 128;    // channels
#define ALPHA_F ((float)(8.0/9.0))
#define OMA_F   ((float)(1.0 - 8.0/9.0))

// ---------------------------------------------------------------------------
// KNN v3: 4 threads per point, interleaved quarter scan (j = 4*jj+q), each
// thread keeps a BRANCHLESS sorted top-8 (predicated shift-insert, ~43 VALU
// ops/candidate, no exec-mask churn -> software-pipelined ds_read_b128).
// Stable LDS merge (stride-33 float/int arrays: 2-way bank alias only).
// Grid: (NP/64, NB) = 512 blocks of 256 threads.
// ---------------------------------------------------------------------------
__global__ __launch_bounds__(256) void knn_kernel(const float* __restrict__ xyz,
                                                  int* __restrict__ nbr) {
    __shared__ float4 sp[NP];            // 32 KB
    __shared__ float  md[64][33];        // 8.25 KB
    __shared__ int    mi[64][33];        // 8.25 KB
    int b = blockIdx.y;
    const float* X = xyz + (size_t)b * 3 * NP;
    for (int m = threadIdx.x; m < NP; m += 256) {
        float x = X[m], y = X[NP + m], z = X[2 * NP + m];
        sp[m] = make_float4(x, y, z, x * x + y * y + z * z);
    }
    __syncthreads();

    int tid = threadIdx.x;
    int p = tid >> 2;                    // local point 0..63
    int q = tid & 3;                     // quarter 0..3
    int base = blockIdx.x * 64;
    int n = base + p;
    float4 me = sp[n];
    float xi = me.x, yi = me.y, zi = me.z, qi = me.w;

    float bd[8]; int bi[8];
#pragma unroll
    for (int t = 0; t < 8; ++t) { bd[t] = 3.4e38f; bi[t] = 0; }

#pragma unroll 4
    for (int jj = 0; jj < NP / 4; ++jj) {
        int j = 4 * jj + q;
        float4 c4v = sp[j];
        float inner = xi * c4v.x + yi * c4v.y + zi * c4v.z;
        float d = qi + c4v.w - 2.0f * inner;
        // branchless sorted insert (strict <, equal keys keep earlier entry)
        bool c[8];
#pragma unroll
        for (int t = 0; t < 8; ++t) c[t] = d < bd[t];
#pragma unroll
        for (int t = 7; t >= 1; --t) {
            bd[t] = c[t - 1] ? bd[t - 1] : (c[t] ? d : bd[t]);
            bi[t] = c[t - 1] ? bi[t - 1] : (c[t] ? j : bi[t]);
        }
        bd[0] = c[0] ? d : bd[0];
        bi[0] = c[0] ? j : bi[0];
    }
#pragma unroll
    for (int t = 0; t < 8; ++t) {
        md[p][q * 8 + t] = bd[t];
        mi[p][q * 8 + t] = bi[t];
    }
    __syncthreads();

    if (tid < 64) {
        float fd[8]; int fi[8];
#pragma unroll
        for (int t = 0; t < 8; ++t) { fd[t] = 3.4e38f; fi[t] = 0; }
#pragma unroll 4
        for (int cc = 0; cc < 32; ++cc) {
            float d = md[tid][cc];
            int j = mi[tid][cc];
            bool c[8];
#pragma unroll
            for (int t = 0; t < 8; ++t) c[t] = d < fd[t];
#pragma unroll
            for (int t = 7; t >= 1; --t) {
                fd[t] = c[t - 1] ? fd[t - 1] : (c[t] ? d : fd[t]);
                fi[t] = c[t - 1] ? fi[t - 1] : (c[t] ? j : fi[t]);
            }
            fd[0] = c[0] ? d : fd[0];
            fi[0] = c[0] ? j : fi[0];
        }
        int row = b * NP + base + tid;
#pragma unroll
        for (int t = 0; t < 7; ++t) nbr[row * 7 + t] = fi[t + 1];
    }
}

// ---------------------------------------------------------------------------
// Generic batched transpose of last two dims: in (B,R,S) -> out (B,S,R)
// grid (S/32, R/32, B), block (32,8)
// ---------------------------------------------------------------------------
__global__ __launch_bounds__(256) void transpose_kernel(const float* __restrict__ in,
                                                        float* __restrict__ out,
                                                        int R, int S) {
    __shared__ float t[32][33];
    int b = blockIdx.z;
    int s0 = blockIdx.x * 32, r0 = blockIdx.y * 32;
    const float* I = in + (size_t)b * R * S;
    float* O = out + (size_t)b * R * S;
#pragma unroll
    for (int i = 0; i < 4; ++i) {
        int r = r0 + threadIdx.y + i * 8;
        t[threadIdx.y + i * 8][threadIdx.x] = I[(size_t)r * S + s0 + threadIdx.x];
    }
    __syncthreads();
#pragma unroll
    for (int i = 0; i < 4; ++i) {
        int s = s0 + threadIdx.y + i * 8;
        O[(size_t)s * R + r0 + threadIdx.x] = t[threadIdx.x][threadIdx.y + i * 8];
    }
}

// ---------------------------------------------------------------------------
// Dual GEMM: Y1 = relu(P) @ Wc^T ; Y2 = P @ Wg^T
// P: (32768,128) row-major. Wc/Wg: (128,128) (out_dim, in_dim).
// Block: 256 thr, tile 64 rows x 128 cols, thread = 4 rows x 8 strided cols.
// kc/kk4 loops pinned to unroll 1: the kk4 body already has 256 independent
// FMAs of ILP; unrolling only inflates VGPR pressure (round-1 spill: VGPR=256,
// 664 MB of scratch traffic).
// ---------------------------------------------------------------------------
__global__ __launch_bounds__(256) void gemm2_kernel(const float* __restrict__ P,
                                                    const float* __restrict__ Wc,
                                                    const float* __restrict__ Wg,
                                                    float* __restrict__ Y1,
                                                    float* __restrict__ Y2) {
    __shared__ float Alds[64][132];     // stride 132: 2-way bank alias only
    __shared__ float Wclds[128][36];    // [out_dim][k-chunk], stride 36
    __shared__ float Wglds[128][36];
    int tid = threadIdx.x;
    int tx = tid & 15, ty = tid >> 4;
    size_t rowBase = (size_t)blockIdx.x * 64;
    const float* Pblk = P + rowBase * NC;

    // Stage A tile (64 x 128), fully coalesced
    {
        const float4* src = (const float4*)Pblk;
#pragma unroll
        for (int m = 0; m < 8; ++m) {
            int f = tid + 256 * m;
            int r = f >> 5, c4 = (f & 31) * 4;
            *((float4*)&Alds[r][c4]) = src[f];
        }
    }

    float accC[4][8], accG[4][8];
#pragma unroll
    for (int i = 0; i < 4; ++i)
#pragma unroll
        for (int j = 0; j < 8; ++j) { accC[i][j] = 0.f; accG[i][j] = 0.f; }

#pragma unroll 1
    for (int kc = 0; kc < 4; ++kc) {
        __syncthreads();   // A ready (kc=0) / previous W chunk consumed
        {
            int d = tid >> 1, h = (tid & 1) * 16;
            const float4* sc = (const float4*)(Wc + d * NC + kc * 32 + h);
            const float4* sg = (const float4*)(Wg + d * NC + kc * 32 + h);
#pragma unroll
            for (int m = 0; m < 4; ++m) {
                *((float4*)&Wclds[d][h + 4 * m]) = sc[m];
                *((float4*)&Wglds[d][h + 4 * m]) = sg[m];
            }
        }
        __syncthreads();
#pragma unroll 1
        for (int kk4 = 0; kk4 < 8; ++kk4) {
            int k = kk4 * 4;
            float4 a[4], ar[4];
#pragma unroll
            for (int i = 0; i < 4; ++i) {
                a[i] = *((const float4*)&Alds[ty * 4 + i][kc * 32 + k]);
                ar[i].x = fmaxf(a[i].x, 0.f);
                ar[i].y = fmaxf(a[i].y, 0.f);
                ar[i].z = fmaxf(a[i].z, 0.f);
                ar[i].w = fmaxf(a[i].w, 0.f);
            }
#pragma unroll
            for (int j = 0; j < 8; ++j) {
                int cc = tx + 16 * j;
                float4 wc = *((const float4*)&Wclds[cc][k]);
                float4 wg = *((const float4*)&Wglds[cc][k]);
#pragma unroll
                for (int i = 0; i < 4; ++i) {
                    accC[i][j] += ar[i].x * wc.x + ar[i].y * wc.y + ar[i].z * wc.z + ar[i].w * wc.w;
                    accG[i][j] += a[i].x * wg.x + a[i].y * wg.y + a[i].z * wg.z + a[i].w * wg.w;
                }
            }
        }
    }
    // Store (strided cols; each 16-lane cluster writes a contiguous 64B run)
#pragma unroll
    for (int i = 0; i < 4; ++i) {
        size_t row = rowBase + ty * 4 + i;
#pragma unroll
        for (int j = 0; j < 8; ++j) {
            Y1[row * NC + tx + 16 * j] = accC[i][j];
            Y2[row * NC + tx + 16 * j] = accG[i][j];
        }
    }
}

// ---------------------------------------------------------------------------
// Aggregate + residual: Pout = P + ALPHA*Y1 + (1-ALPHA)*( (Y2[n]+sum_nbr)/8 )
// 32 threads (float4 each) per row; 8 rows per block.
// ---------------------------------------------------------------------------
__global__ __launch_bounds__(256) void agg_kernel(const float* __restrict__ P,
                                                  const float* __restrict__ Y1,
                                                  const float* __restrict__ Y2,
                                                  const int* __restrict__ nbr,
                                                  float* __restrict__ Pout) {
    int tid = threadIdx.x;
    int lane = tid & 31, rl = tid >> 5;
    size_t row = (size_t)blockIdx.x * 8 + rl;
    int b = (int)(row >> 11);
    const int* nb = nbr + row * 7;
    size_t off = row * NC + lane * 4;
    float4 ys = *((const float4*)(Y2 + off));
    size_t bbase = (size_t)b * NP * NC;
#pragma unroll
    for (int t = 0; t < 7; ++t) {
        int j = nb[t];
        float4 v = *((const float4*)(Y2 + bbase + (size_t)j * NC + lane * 4));
        ys.x += v.x; ys.y += v.y; ys.z += v.z; ys.w += v.w;
    }
    float4 p = *((const float4*)(P + off));
    float4 y1 = *((const float4*)(Y1 + off));
    float4 o;
    o.x = OMA_F * (0.125f * ys.x) + ALPHA_F * y1.x + p.x;
    o.y = OMA_F * (0.125f * ys.y) + ALPHA_F * y1.y + p.y;
    o.z = OMA_F * (0.125f * ys.z) + ALPHA_F * y1.z + p.z;
    o.w = OMA_F * (0.125f * ys.w) + ALPHA_F * y1.w + p.w;
    *((float4*)(Pout + off)) = o;
}

// ---------------------------------------------------------------------------
// Final small GEMMs: U1 = P @ Wuc^T (6), U2 = P @ Wug^T (6); U row = [U1|U2]
// One thread per row.
// ---------------------------------------------------------------------------
__global__ __launch_bounds__(256) void final_gemm_kernel(const float* __restrict__ P,
                                                         const float* __restrict__ Wuc,
                                                         const float* __restrict__ Wug,
                                                         float* __restrict__ U) {
    __shared__ float s1[6 * NC], s2[6 * NC];
    for (int m = threadIdx.x; m < 6 * NC; m += 256) { s1[m] = Wuc[m]; s2[m] = Wug[m]; }
    __syncthreads();
    size_t row = (size_t)blockIdx.x * 256 + threadIdx.x;
    const float4* prow = (const float4*)(P + row * NC);
    float a1[6] = {0, 0, 0, 0, 0, 0}, a2[6] = {0, 0, 0, 0, 0, 0};
#pragma unroll 4
    for (int c4 = 0; c4 < NC / 4; ++c4) {
        float4 p = prow[c4];
#pragma unroll
        for (int o = 0; o < 6; ++o) {
            float4 w1 = *((const float4*)&s1[o * NC + c4 * 4]);
            float4 w2 = *((const float4*)&s2[o * NC + c4 * 4]);
            a1[o] += p.x * w1.x + p.y * w1.y + p.z * w1.z + p.w * w1.w;
            a2[o] += p.x * w2.x + p.y * w2.y + p.z * w2.z + p.w * w2.w;
        }
    }
#pragma unroll
    for (int o = 0; o < 6; ++o) {
        U[row * 12 + o] = a1[o];
        U[row * 12 + 6 + o] = a2[o];
    }
}

// ---------------------------------------------------------------------------
// Final output: new_xyz[b][c][s*N+n] = ALPHA*U1[o]+ (1-ALPHA)*(aggU2[o]/8) + xyz[b][c][n]
// (o = 2c+s). One thread per (b,n).
// ---------------------------------------------------------------------------
__global__ __launch_bounds__(256) void final_out_kernel(const float* __restrict__ U,
                                                        const int* __restrict__ nbr,
                                                        const float* __restrict__ xyz,
                                                        float* __restrict__ out) {
    size_t row = (size_t)blockIdx.x * 256 + threadIdx.x;
    int b = (int)(row >> 11), n = (int)(row & 2047);
    const int* nb = nbr + row * 7;
    float u1[6], u2[6];
#pragma unroll
    for (int o = 0; o < 6; ++o) { u1[o] = U[row * 12 + o]; u2[o] = U[row * 12 + 6 + o]; }
#pragma unroll
    for (int t = 0; t < 7; ++t) {
        int j = nb[t];
        const float* Uj = U + ((size_t)b * NP + j) * 12 + 6;
#pragma unroll
        for (int o = 0; o < 6; ++o) u2[o] += Uj[o];
    }
#pragma unroll
    for (int c = 0; c < 3; ++c)
#pragma unroll
        for (int s = 0; s < 2; ++s) {
            int o = c * 2 + s;
            float val = ALPHA_F * u1[o] + OMA_F * (0.125f * u2[o])
                      + xyz[(size_t)b * 3 * NP + (size_t)c * NP + n];
            out[(size_t)b * 3 * 2 * NP + (size_t)c * 2 * NP + (size_t)s * NP + n] = val;
        }
}

// ---------------------------------------------------------------------------
extern "C" void kernel_launch(void* const* d_in, const int* in_sizes, int n_in,
                              void* d_out, int out_size, void* d_ws, size_t ws_size,
                              hipStream_t stream) {
    const float* xyz    = (const float*)d_in[0];  // (16,3,2048)
    const float* points = (const float*)d_in[1];  // (16,128,2048)
    const float* Wc     = (const float*)d_in[2];  // (4,128,128)
    const float* Wg     = (const float*)d_in[3];  // (4,128,128)
    const float* Wuc    = (const float*)d_in[4];  // (6,128)
    const float* Wug    = (const float*)d_in[5];  // (6,128)
    float* out = (float*)d_out;

    char* ws = (char*)d_ws;
    size_t o = 0;
    int* nbr = (int*)(ws + o);      o += (size_t)NB * NP * 7 * 4;      // 917504
    float* P0 = (float*)(ws + o);   o += (size_t)NB * NP * NC * 4;     // 16 MB
    float* P1 = (float*)(ws + o);   o += (size_t)NB * NP * NC * 4;
    float* Y1 = (float*)(ws + o);   o += (size_t)NB * NP * NC * 4;
    float* Y2 = (float*)(ws + o);   o += (size_t)NB * NP * NC * 4;
    float* U  = (float*)(ws + o);   o += (size_t)NB * NP * 12 * 4;

    // 1) points (B,C,N) -> P0 (B,N,C)
    transpose_kernel<<<dim3(NP / 32, NC / 32, NB), dim3(32, 8), 0, stream>>>(points, P0, NC, NP);
    // 2) KNN
    knn_kernel<<<dim3(NP / 64, NB), 256, 0, stream>>>(xyz, nbr);
    // 3) 4 GCN blocks (ping-pong P0<->P1)
    float* Pin = P0; float* Pout = P1;
    for (int i = 0; i < 4; ++i) {
        gemm2_kernel<<<dim3(NB * NP / 64), 256, 0, stream>>>(
            Pin, Wc + (size_t)i * NC * NC, Wg + (size_t)i * NC * NC, Y1, Y2);
        agg_kernel<<<dim3(NB * NP / 8), 256, 0, stream>>>(Pin, Y1, Y2, nbr, Pout);
        float* tmp = Pin; Pin = Pout; Pout = tmp;
    }
    // Pin now holds final pts (B,N,C)
    // 4) final small GEMMs
    final_gemm_kernel<<<dim3(NB * NP / 256), 256, 0, stream>>>(Pin, Wuc, Wug, U);
    // 5) new_xyz
    final_out_kernel<<<dim3(NB * NP / 256), 256, 0, stream>>>(U, nbr, xyz, out);
    // 6) pts (B,N,C) -> out2 (B,C,N)
    transpose_kernel<<<dim3(NC / 32, NP / 32, NB), dim3(32, 8), 0, stream>>>(
        Pin, out + (size_t)NB * 3 * 2 * NP, NP, NC);
}

// Round 4
// 332.807 us; speedup vs baseline: 4.0524x; 1.3781x over previous
//
#include <hip/hip_runtime.h>
#include <hip/hip_bf16.h>

// Problem constants
static constexpr int NB = 16;     // batches
static constexpr int NP = 2048;   // points per batch
static constexpr int NC = 128;    // channels
#define ALPHA_F ((float)(8.0/9.0))
#define OMA_F   ((float)(1.0 - 8.0/9.0))

typedef __attribute__((ext_vector_type(8))) short bfrag;   // 8 bf16 (4 VGPR)
typedef __attribute__((ext_vector_type(4))) float ffrag;   // 4 fp32 acc

union BU { bfrag v; uint4 u; unsigned int w[4]; };

// split two floats into packed bf16 hi pair + write back hi as fp32
__device__ inline void split2(float x, float y, unsigned& hi, unsigned& lo) {
    __hip_bfloat162 h = __float22bfloat162_rn(make_float2(x, y));
    float2 hb = __bfloat1622float2(h);
    __hip_bfloat162 l = __float22bfloat162_rn(make_float2(x - hb.x, y - hb.y));
    __builtin_memcpy(&hi, &h, 4);
    __builtin_memcpy(&lo, &l, 4);
}

// ---------------------------------------------------------------------------
// KNN v3 (unchanged): branchless top-8, 4 threads/point.
// ---------------------------------------------------------------------------
__global__ __launch_bounds__(256) void knn_kernel(const float* __restrict__ xyz,
                                                  int* __restrict__ nbr) {
    __shared__ float4 sp[NP];            // 32 KB
    __shared__ float  md[64][33];
    __shared__ int    mi[64][33];
    int b = blockIdx.y;
    const float* X = xyz + (size_t)b * 3 * NP;
    for (int m = threadIdx.x; m < NP; m += 256) {
        float x = X[m], y = X[NP + m], z = X[2 * NP + m];
        sp[m] = make_float4(x, y, z, x * x + y * y + z * z);
    }
    __syncthreads();

    int tid = threadIdx.x;
    int p = tid >> 2;
    int q = tid & 3;
    int base = blockIdx.x * 64;
    int n = base + p;
    float4 me = sp[n];
    float xi = me.x, yi = me.y, zi = me.z, qi = me.w;

    float bd[8]; int bi[8];
#pragma unroll
    for (int t = 0; t < 8; ++t) { bd[t] = 3.4e38f; bi[t] = 0; }

#pragma unroll 4
    for (int jj = 0; jj < NP / 4; ++jj) {
        int j = 4 * jj + q;
        float4 c4v = sp[j];
        float inner = xi * c4v.x + yi * c4v.y + zi * c4v.z;
        float d = qi + c4v.w - 2.0f * inner;
        bool c[8];
#pragma unroll
        for (int t = 0; t < 8; ++t) c[t] = d < bd[t];
#pragma unroll
        for (int t = 7; t >= 1; --t) {
            bd[t] = c[t - 1] ? bd[t - 1] : (c[t] ? d : bd[t]);
            bi[t] = c[t - 1] ? bi[t - 1] : (c[t] ? j : bi[t]);
        }
        bd[0] = c[0] ? d : bd[0];
        bi[0] = c[0] ? j : bi[0];
    }
#pragma unroll
    for (int t = 0; t < 8; ++t) {
        md[p][q * 8 + t] = bd[t];
        mi[p][q * 8 + t] = bi[t];
    }
    __syncthreads();

    if (tid < 64) {
        float fd[8]; int fi[8];
#pragma unroll
        for (int t = 0; t < 8; ++t) { fd[t] = 3.4e38f; fi[t] = 0; }
#pragma unroll 4
        for (int cc = 0; cc < 32; ++cc) {
            float d = md[tid][cc];
            int j = mi[tid][cc];
            bool c[8];
#pragma unroll
            for (int t = 0; t < 8; ++t) c[t] = d < fd[t];
#pragma unroll
            for (int t = 7; t >= 1; --t) {
                fd[t] = c[t - 1] ? fd[t - 1] : (c[t] ? d : fd[t]);
                fi[t] = c[t - 1] ? fi[t - 1] : (c[t] ? j : fi[t]);
            }
            fd[0] = c[0] ? d : fd[0];
            fi[0] = c[0] ? j : fi[0];
        }
        int row = b * NP + base + tid;
#pragma unroll
        for (int t = 0; t < 7; ++t) nbr[row * 7 + t] = fi[t + 1];
    }
}

// ---------------------------------------------------------------------------
// Generic batched transpose of last two dims: in (B,R,S) -> out (B,S,R)
// ---------------------------------------------------------------------------
__global__ __launch_bounds__(256) void transpose_kernel(const float* __restrict__ in,
                                                        float* __restrict__ out,
                                                        int R, int S) {
    __shared__ float t[32][33];
    int b = blockIdx.z;
    int s0 = blockIdx.x * 32, r0 = blockIdx.y * 32;
    const float* I = in + (size_t)b * R * S;
    float* O = out + (size_t)b * R * S;
#pragma unroll
    for (int i = 0; i < 4; ++i) {
        int r = r0 + threadIdx.y + i * 8;
        t[threadIdx.y + i * 8][threadIdx.x] = I[(size_t)r * S + s0 + threadIdx.x];
    }
    __syncthreads();
#pragma unroll
    for (int i = 0; i < 4; ++i) {
        int s = s0 + threadIdx.y + i * 8;
        O[(size_t)s * R + r0 + threadIdx.x] = t[threadIdx.x][threadIdx.y + i * 8];
    }
}

// ---------------------------------------------------------------------------
// MFMA dual GEMM via split-bf16 (x = hi + lo; x*w ~ hi*hi + hi*lo + lo*hi):
//   Z  = P + ALPHA * ( relu(P) @ Wc^T )      (fused residual+center epilogue)
//   Y2 = P @ Wg^T
// Block: 512 thr (8 waves), M-strip = 64 rows, full N=128 (wave w -> cols
// [16w,16w+16)). A staged in LDS as separate Ah/Al bf16 planes (u32-packed,
// row stride 68 -> stride-1-equivalent bank pattern). Relu variants derived
// in-register from Ah sign bits: relu(x) splits to (mask(Ah), mask(Al)).
// W split lives in VGPRs (16 frags = 64 regs), loaded once per block.
// ---------------------------------------------------------------------------
__global__ __launch_bounds__(512) void gemm2_mfma_kernel(const float* __restrict__ P,
                                                         const float* __restrict__ Wc,
                                                         const float* __restrict__ Wg,
                                                         float* __restrict__ Z,
                                                         float* __restrict__ Y2) {
    __shared__ unsigned int AhT[64][68];   // 17.4 KB
    __shared__ unsigned int AlT[64][68];   // 17.4 KB
    int tid = threadIdx.x;
    int wid = tid >> 6, lane = tid & 63;
    int quad = lane >> 4, l15 = lane & 15;
    size_t m0 = (size_t)blockIdx.x * 64;

    // ---- B-frags: lane holds W[n = 16*wid + l15][k = 32s + 8*quad + j]
    int ncol = wid * 16 + l15;
    const float* wcr = Wc + (size_t)ncol * NC + quad * 8;
    const float* wgr = Wg + (size_t)ncol * NC + quad * 8;
    BU Bch[4], Bcl[4], Bgh[4], Bgl[4];
#pragma unroll
    for (int s = 0; s < 4; ++s) {
        float4 c0 = *((const float4*)(wcr + s * 32));
        float4 c1 = *((const float4*)(wcr + s * 32 + 4));
        split2(c0.x, c0.y, Bch[s].w[0], Bcl[s].w[0]);
        split2(c0.z, c0.w, Bch[s].w[1], Bcl[s].w[1]);
        split2(c1.x, c1.y, Bch[s].w[2], Bcl[s].w[2]);
        split2(c1.z, c1.w, Bch[s].w[3], Bcl[s].w[3]);
        float4 g0 = *((const float4*)(wgr + s * 32));
        float4 g1 = *((const float4*)(wgr + s * 32 + 4));
        split2(g0.x, g0.y, Bgh[s].w[0], Bgl[s].w[0]);
        split2(g0.z, g0.w, Bgh[s].w[1], Bgl[s].w[1]);
        split2(g1.x, g1.y, Bgh[s].w[2], Bgl[s].w[2]);
        split2(g1.z, g1.w, Bgh[s].w[3], Bgl[s].w[3]);
    }

    // ---- stage A strip (64 x 128 fp32 -> Ah/Al bf16 planes)
#pragma unroll
    for (int it = 0; it < 4; ++it) {
        int f = tid + it * 512;
        int r = f >> 5, c = (f & 31) * 4;
        float4 v = *((const float4*)(P + (m0 + r) * NC + c));
        unsigned h01, l01, h23, l23;
        split2(v.x, v.y, h01, l01);
        split2(v.z, v.w, h23, l23);
        *((uint2*)&AhT[r][c >> 1]) = make_uint2(h01, h23);
        *((uint2*)&AlT[r][c >> 1]) = make_uint2(l01, l23);
    }
    __syncthreads();

    ffrag accC[4], accG[4];
#pragma unroll
    for (int mt = 0; mt < 4; ++mt) { accC[mt] = (ffrag)0.0f; accG[mt] = (ffrag)0.0f; }

#pragma unroll
    for (int s = 0; s < 4; ++s) {
#pragma unroll
        for (int mt = 0; mt < 4; ++mt) {
            int m = mt * 16 + l15;
            int ku = s * 16 + quad * 4;
            BU ah, al, rh, rl;
            ah.u = *((const uint4*)&AhT[m][ku]);
            al.u = *((const uint4*)&AlT[m][ku]);
#pragma unroll
            for (int w = 0; w < 4; ++w) {
                unsigned neg = ah.w[w] & 0x80008000u;
                unsigned msk = (neg >> 15) * 0xFFFFu;   // FFFF per negative half
                rh.w[w] = ah.w[w] & ~msk;
                rl.w[w] = al.w[w] & ~msk;
            }
            accC[mt] = __builtin_amdgcn_mfma_f32_16x16x32_bf16(rh.v, Bch[s].v, accC[mt], 0, 0, 0);
            accC[mt] = __builtin_amdgcn_mfma_f32_16x16x32_bf16(rh.v, Bcl[s].v, accC[mt], 0, 0, 0);
            accC[mt] = __builtin_amdgcn_mfma_f32_16x16x32_bf16(rl.v, Bch[s].v, accC[mt], 0, 0, 0);
            accG[mt] = __builtin_amdgcn_mfma_f32_16x16x32_bf16(ah.v, Bgh[s].v, accG[mt], 0, 0, 0);
            accG[mt] = __builtin_amdgcn_mfma_f32_16x16x32_bf16(ah.v, Bgl[s].v, accG[mt], 0, 0, 0);
            accG[mt] = __builtin_amdgcn_mfma_f32_16x16x32_bf16(al.v, Bgh[s].v, accG[mt], 0, 0, 0);
        }
    }

    // ---- epilogue: C/D layout col = l15, row = 4*quad + r
#pragma unroll
    for (int mt = 0; mt < 4; ++mt) {
        int rbase = mt * 16 + quad * 4;
#pragma unroll
        for (int r = 0; r < 4; ++r) {
            size_t idx = (m0 + rbase + r) * NC + ncol;
            float p = P[idx];                   // L2-hot (staged above)
            Z[idx] = p + ALPHA_F * accC[mt][r];
            Y2[idx] = accG[mt][r];
        }
    }
}

// ---------------------------------------------------------------------------
// Aggregate: Pout = Z + (1-ALPHA) * ( (Y2[n] + sum_nbr Y2) / 8 )
// ---------------------------------------------------------------------------
__global__ __launch_bounds__(256) void agg_kernel(const float* __restrict__ Z,
                                                  const float* __restrict__ Y2,
                                                  const int* __restrict__ nbr,
                                                  float* __restrict__ Pout) {
    int tid = threadIdx.x;
    int lane = tid & 31, rl = tid >> 5;
    size_t row = (size_t)blockIdx.x * 8 + rl;
    int b = (int)(row >> 11);
    const int* nb = nbr + row * 7;
    size_t off = row * NC + lane * 4;
    float4 ys = *((const float4*)(Y2 + off));
    size_t bbase = (size_t)b * NP * NC;
#pragma unroll
    for (int t = 0; t < 7; ++t) {
        int j = nb[t];
        float4 v = *((const float4*)(Y2 + bbase + (size_t)j * NC + lane * 4));
        ys.x += v.x; ys.y += v.y; ys.z += v.z; ys.w += v.w;
    }
    float4 z = *((const float4*)(Z + off));
    float4 o;
    o.x = OMA_F * (0.125f * ys.x) + z.x;
    o.y = OMA_F * (0.125f * ys.y) + z.y;
    o.z = OMA_F * (0.125f * ys.z) + z.z;
    o.w = OMA_F * (0.125f * ys.w) + z.w;
    *((float4*)(Pout + off)) = o;
}

// ---------------------------------------------------------------------------
// Final small GEMMs: U1 = P @ Wuc^T (6), U2 = P @ Wug^T (6); U row = [U1|U2]
// ---------------------------------------------------------------------------
__global__ __launch_bounds__(256) void final_gemm_kernel(const float* __restrict__ P,
                                                         const float* __restrict__ Wuc,
                                                         const float* __restrict__ Wug,
                                                         float* __restrict__ U) {
    __shared__ float s1[6 * NC], s2[6 * NC];
    for (int m = threadIdx.x; m < 6 * NC; m += 256) { s1[m] = Wuc[m]; s2[m] = Wug[m]; }
    __syncthreads();
    size_t row = (size_t)blockIdx.x * 256 + threadIdx.x;
    const float4* prow = (const float4*)(P + row * NC);
    float a1[6] = {0, 0, 0, 0, 0, 0}, a2[6] = {0, 0, 0, 0, 0, 0};
#pragma unroll 4
    for (int c4 = 0; c4 < NC / 4; ++c4) {
        float4 p = prow[c4];
#pragma unroll
        for (int o = 0; o < 6; ++o) {
            float4 w1 = *((const float4*)&s1[o * NC + c4 * 4]);
            float4 w2 = *((const float4*)&s2[o * NC + c4 * 4]);
            a1[o] += p.x * w1.x + p.y * w1.y + p.z * w1.z + p.w * w1.w;
            a2[o] += p.x * w2.x + p.y * w2.y + p.z * w2.z + p.w * w2.w;
        }
    }
#pragma unroll
    for (int o = 0; o < 6; ++o) {
        U[row * 12 + o] = a1[o];
        U[row * 12 + 6 + o] = a2[o];
    }
}

// ---------------------------------------------------------------------------
// Final output: new_xyz
// ---------------------------------------------------------------------------
__global__ __launch_bounds__(256) void final_out_kernel(const float* __restrict__ U,
                                                        const int* __restrict__ nbr,
                                                        const float* __restrict__ xyz,
                                                        float* __restrict__ out) {
    size_t row = (size_t)blockIdx.x * 256 + threadIdx.x;
    int b = (int)(row >> 11), n = (int)(row & 2047);
    const int* nb = nbr + row * 7;
    float u1[6], u2[6];
#pragma unroll
    for (int o = 0; o < 6; ++o) { u1[o] = U[row * 12 + o]; u2[o] = U[row * 12 + 6 + o]; }
#pragma unroll
    for (int t = 0; t < 7; ++t) {
        int j = nb[t];
        const float* Uj = U + ((size_t)b * NP + j) * 12 + 6;
#pragma unroll
        for (int o = 0; o < 6; ++o) u2[o] += Uj[o];
    }
#pragma unroll
    for (int c = 0; c < 3; ++c)
#pragma unroll
        for (int s = 0; s < 2; ++s) {
            int o = c * 2 + s;
            float val = ALPHA_F * u1[o] + OMA_F * (0.125f * u2[o])
                      + xyz[(size_t)b * 3 * NP + (size_t)c * NP + n];
            out[(size_t)b * 3 * 2 * NP + (size_t)c * 2 * NP + (size_t)s * NP + n] = val;
        }
}

// ---------------------------------------------------------------------------
extern "C" void kernel_launch(void* const* d_in, const int* in_sizes, int n_in,
                              void* d_out, int out_size, void* d_ws, size_t ws_size,
                              hipStream_t stream) {
    const float* xyz    = (const float*)d_in[0];  // (16,3,2048)
    const float* points = (const float*)d_in[1];  // (16,128,2048)
    const float* Wc     = (const float*)d_in[2];  // (4,128,128)
    const float* Wg     = (const float*)d_in[3];  // (4,128,128)
    const float* Wuc    = (const float*)d_in[4];  // (6,128)
    const float* Wug    = (const float*)d_in[5];  // (6,128)
    float* out = (float*)d_out;

    char* ws = (char*)d_ws;
    size_t o = 0;
    int* nbr = (int*)(ws + o);      o += (size_t)NB * NP * 7 * 4;
    float* P0 = (float*)(ws + o);   o += (size_t)NB * NP * NC * 4;     // 16 MB
    float* P1 = (float*)(ws + o);   o += (size_t)NB * NP * NC * 4;
    float* Zb = (float*)(ws + o);   o += (size_t)NB * NP * NC * 4;
    float* Y2 = (float*)(ws + o);   o += (size_t)NB * NP * NC * 4;
    float* U  = (float*)(ws + o);   o += (size_t)NB * NP * 12 * 4;

    // 1) points (B,C,N) -> P0 (B,N,C)
    transpose_kernel<<<dim3(NP / 32, NC / 32, NB), dim3(32, 8), 0, stream>>>(points, P0, NC, NP);
    // 2) KNN
    knn_kernel<<<dim3(NP / 64, NB), 256, 0, stream>>>(xyz, nbr);
    // 3) 4 GCN blocks (ping-pong P0<->P1)
    float* Pin = P0; float* Pout = P1;
    for (int i = 0; i < 4; ++i) {
        gemm2_mfma_kernel<<<dim3(NB * NP / 64), 512, 0, stream>>>(
            Pin, Wc + (size_t)i * NC * NC, Wg + (size_t)i * NC * NC, Zb, Y2);
        agg_kernel<<<dim3(NB * NP / 8), 256, 0, stream>>>(Zb, Y2, nbr, Pout);
        float* tmp = Pin; Pin = Pout; Pout = tmp;
    }
    // 4) final small GEMMs
    final_gemm_kernel<<<dim3(NB * NP / 256), 256, 0, stream>>>(Pin, Wuc, Wug, U);
    // 5) new_xyz
    final_out_kernel<<<dim3(NB * NP / 256), 256, 0, stream>>>(U, nbr, xyz, out);
    // 6) pts (B,N,C) -> out2 (B,C,N)
    transpose_kernel<<<dim3(NC / 32, NP / 32, NB), dim3(32, 8), 0, stream>>>(
        Pin, out + (size_t)NB * 3 * 2 * NP, NP, NC);
}

// Round 5
// 309.519 us; speedup vs baseline: 4.3573x; 1.0752x over previous
//
#include <hip/hip_runtime.h>
#include <hip/hip_bf16.h>

// Problem constants
static constexpr int NB = 16;     // batches
static constexpr int NP = 2048;   // points per batch
static constexpr int NC = 128;    // channels
#define ALPHA_F ((float)(8.0/9.0))
#define OMA_F   ((float)(1.0 - 8.0/9.0))

typedef __attribute__((ext_vector_type(8))) short bfrag;   // 8 bf16 (4 VGPR)
typedef __attribute__((ext_vector_type(4))) float ffrag;   // 4 fp32 acc

union BU { bfrag v; uint4 u; unsigned int w[4]; };

// split two floats into packed bf16 hi pair + bf16 lo pair
__device__ inline void split2(float x, float y, unsigned& hi, unsigned& lo) {
    __hip_bfloat162 h = __float22bfloat162_rn(make_float2(x, y));
    float2 hb = __bfloat1622float2(h);
    __hip_bfloat162 l = __float22bfloat162_rn(make_float2(x - hb.x, y - hb.y));
    __builtin_memcpy(&hi, &h, 4);
    __builtin_memcpy(&lo, &l, 4);
}

// ---------------------------------------------------------------------------
// KNN v3 (unchanged): branchless top-8, 4 threads/point.
// ---------------------------------------------------------------------------
__global__ __launch_bounds__(256) void knn_kernel(const float* __restrict__ xyz,
                                                  int* __restrict__ nbr) {
    __shared__ float4 sp[NP];            // 32 KB
    __shared__ float  md[64][33];
    __shared__ int    mi[64][33];
    int b = blockIdx.y;
    const float* X = xyz + (size_t)b * 3 * NP;
    for (int m = threadIdx.x; m < NP; m += 256) {
        float x = X[m], y = X[NP + m], z = X[2 * NP + m];
        sp[m] = make_float4(x, y, z, x * x + y * y + z * z);
    }
    __syncthreads();

    int tid = threadIdx.x;
    int p = tid >> 2;
    int q = tid & 3;
    int base = blockIdx.x * 64;
    int n = base + p;
    float4 me = sp[n];
    float xi = me.x, yi = me.y, zi = me.z, qi = me.w;

    float bd[8]; int bi[8];
#pragma unroll
    for (int t = 0; t < 8; ++t) { bd[t] = 3.4e38f; bi[t] = 0; }

#pragma unroll 4
    for (int jj = 0; jj < NP / 4; ++jj) {
        int j = 4 * jj + q;
        float4 c4v = sp[j];
        float inner = xi * c4v.x + yi * c4v.y + zi * c4v.z;
        float d = qi + c4v.w - 2.0f * inner;
        bool c[8];
#pragma unroll
        for (int t = 0; t < 8; ++t) c[t] = d < bd[t];
#pragma unroll
        for (int t = 7; t >= 1; --t) {
            bd[t] = c[t - 1] ? bd[t - 1] : (c[t] ? d : bd[t]);
            bi[t] = c[t - 1] ? bi[t - 1] : (c[t] ? j : bi[t]);
        }
        bd[0] = c[0] ? d : bd[0];
        bi[0] = c[0] ? j : bi[0];
    }
#pragma unroll
    for (int t = 0; t < 8; ++t) {
        md[p][q * 8 + t] = bd[t];
        mi[p][q * 8 + t] = bi[t];
    }
    __syncthreads();

    if (tid < 64) {
        float fd[8]; int fi[8];
#pragma unroll
        for (int t = 0; t < 8; ++t) { fd[t] = 3.4e38f; fi[t] = 0; }
#pragma unroll 4
        for (int cc = 0; cc < 32; ++cc) {
            float d = md[tid][cc];
            int j = mi[tid][cc];
            bool c[8];
#pragma unroll
            for (int t = 0; t < 8; ++t) c[t] = d < fd[t];
#pragma unroll
            for (int t = 7; t >= 1; --t) {
                fd[t] = c[t - 1] ? fd[t - 1] : (c[t] ? d : fd[t]);
                fi[t] = c[t - 1] ? fi[t - 1] : (c[t] ? j : fi[t]);
            }
            fd[0] = c[0] ? d : fd[0];
            fi[0] = c[0] ? j : fi[0];
        }
        int row = b * NP + base + tid;
#pragma unroll
        for (int t = 0; t < 7; ++t) nbr[row * 7 + t] = fi[t + 1];
    }
}

// ---------------------------------------------------------------------------
// Generic batched transpose of last two dims: in (B,R,S) -> out (B,S,R)
// ---------------------------------------------------------------------------
__global__ __launch_bounds__(256) void transpose_kernel(const float* __restrict__ in,
                                                        float* __restrict__ out,
                                                        int R, int S) {
    __shared__ float t[32][33];
    int b = blockIdx.z;
    int s0 = blockIdx.x * 32, r0 = blockIdx.y * 32;
    const float* I = in + (size_t)b * R * S;
    float* O = out + (size_t)b * R * S;
#pragma unroll
    for (int i = 0; i < 4; ++i) {
        int r = r0 + threadIdx.y + i * 8;
        t[threadIdx.y + i * 8][threadIdx.x] = I[(size_t)r * S + s0 + threadIdx.x];
    }
    __syncthreads();
#pragma unroll
    for (int i = 0; i < 4; ++i) {
        int s = s0 + threadIdx.y + i * 8;
        O[(size_t)s * R + r0 + threadIdx.x] = t[threadIdx.x][threadIdx.y + i * 8];
    }
}

// ---------------------------------------------------------------------------
// Fused GCN block (MFMA split-bf16):
//   MODE 0: A = points^T tile (reads points in (B,C,N) directly — transpose fused)
//   MODE 1: A = Zprev + (1-ALPHA) * ((Y2prev[self] + sum_nbr Y2prev)/8)
//           (previous layer's agg fused into this layer's A-staging)
//   Outputs: Zout = A + ALPHA * (relu(A) @ Wc^T) ;  Y2out = A @ Wg^T
// Block: 512 thr (8 waves), tile 64 rows x 128 cols.
// A staged as fp32 LDS plane (also serves epilogue residual read), then split
// into Ah/Al bf16 planes for 3-product MFMA (hi*hi + hi*lo + lo*hi).
// ---------------------------------------------------------------------------
template <int MODE>
__global__ __launch_bounds__(512) void gemm_fused_kernel(const float* __restrict__ Asrc,
                                                         const float* __restrict__ Y2in,
                                                         const int* __restrict__ nbr,
                                                         const float* __restrict__ Wc,
                                                         const float* __restrict__ Wg,
                                                         float* __restrict__ Zout,
                                                         float* __restrict__ Y2out) {
    __shared__ float Afp32[64][132];       // 33.8 KB (fp32 A tile, stride 132)
    __shared__ unsigned int AhT[64][68];   // 17.4 KB
    __shared__ unsigned int AlT[64][68];   // 17.4 KB
    __shared__ int s_nb[448];              // 1.75 KB (64 rows x 7 nbrs)
    int tid = threadIdx.x;
    int wid = tid >> 6, lane = tid & 63;
    int quad = lane >> 4, l15 = lane & 15;
    int bb = blockIdx.x >> 5;              // batch
    int n0 = (blockIdx.x & 31) << 6;       // tile row base within batch
    size_t m0 = (size_t)bb * NP + n0;      // global row base

    // ---- phase 0/1: stage A tile (fp32) into LDS
    if (MODE == 1) {
        if (tid < 448) s_nb[tid] = nbr[m0 * 7 + tid];
        __syncthreads();
        size_t bbase = (size_t)bb * NP;
#pragma unroll 1
        for (int it = 0; it < 4; ++it) {
            int f = tid + it * 512;
            int r = f >> 5, c4 = (f & 31) * 4;
            size_t row = m0 + r;
            float4 z = *((const float4*)(Asrc + row * NC + c4));
            float4 acc = *((const float4*)(Y2in + row * NC + c4));
#pragma unroll
            for (int t = 0; t < 7; ++t) {
                int j = s_nb[r * 7 + t];
                float4 v = *((const float4*)(Y2in + (bbase + (size_t)j) * NC + c4));
                acc.x += v.x; acc.y += v.y; acc.z += v.z; acc.w += v.w;
            }
            float4 a;
            a.x = OMA_F * (0.125f * acc.x) + z.x;
            a.y = OMA_F * (0.125f * acc.y) + z.y;
            a.z = OMA_F * (0.125f * acc.z) + z.z;
            a.w = OMA_F * (0.125f * acc.w) + z.w;
            *((float4*)&Afp32[r][c4]) = a;
        }
    } else {
        // A[r][c] = points[b][c][n0+r]  (contiguous 64-float runs per channel)
#pragma unroll
        for (int it = 0; it < 4; ++it) {
            int f = tid + it * 512;
            int c = f >> 4, rq = (f & 15) * 4;
            float4 v = *((const float4*)(Asrc + ((size_t)bb * NC + c) * NP + n0 + rq));
            Afp32[rq][c] = v.x; Afp32[rq + 1][c] = v.y;
            Afp32[rq + 2][c] = v.z; Afp32[rq + 3][c] = v.w;
        }
    }

    // ---- B-frags (issued here so the W loads overlap the staging barrier):
    // lane holds W[n = 16*wid + l15][k = 32s + 8*quad + j]
    int ncol = wid * 16 + l15;
    const float* wcr = Wc + (size_t)ncol * NC + quad * 8;
    const float* wgr = Wg + (size_t)ncol * NC + quad * 8;
    BU Bch[4], Bcl[4], Bgh[4], Bgl[4];
#pragma unroll
    for (int s = 0; s < 4; ++s) {
        float4 c0 = *((const float4*)(wcr + s * 32));
        float4 c1 = *((const float4*)(wcr + s * 32 + 4));
        split2(c0.x, c0.y, Bch[s].w[0], Bcl[s].w[0]);
        split2(c0.z, c0.w, Bch[s].w[1], Bcl[s].w[1]);
        split2(c1.x, c1.y, Bch[s].w[2], Bcl[s].w[2]);
        split2(c1.z, c1.w, Bch[s].w[3], Bcl[s].w[3]);
        float4 g0 = *((const float4*)(wgr + s * 32));
        float4 g1 = *((const float4*)(wgr + s * 32 + 4));
        split2(g0.x, g0.y, Bgh[s].w[0], Bgl[s].w[0]);
        split2(g0.z, g0.w, Bgh[s].w[1], Bgl[s].w[1]);
        split2(g1.x, g1.y, Bgh[s].w[2], Bgl[s].w[2]);
        split2(g1.z, g1.w, Bgh[s].w[3], Bgl[s].w[3]);
    }
    __syncthreads();

    // ---- split A into bf16 hi/lo planes
#pragma unroll
    for (int it = 0; it < 4; ++it) {
        int f = tid + it * 512;
        int r = f >> 5, c4 = (f & 31) * 4;
        float4 v = *((const float4*)&Afp32[r][c4]);
        unsigned h01, l01, h23, l23;
        split2(v.x, v.y, h01, l01);
        split2(v.z, v.w, h23, l23);
        *((uint2*)&AhT[r][c4 >> 1]) = make_uint2(h01, h23);
        *((uint2*)&AlT[r][c4 >> 1]) = make_uint2(l01, l23);
    }
    __syncthreads();

    ffrag accC[4], accG[4];
#pragma unroll
    for (int mt = 0; mt < 4; ++mt) { accC[mt] = (ffrag)0.0f; accG[mt] = (ffrag)0.0f; }

#pragma unroll
    for (int s = 0; s < 4; ++s) {
#pragma unroll
        for (int mt = 0; mt < 4; ++mt) {
            int m = mt * 16 + l15;
            int ku = s * 16 + quad * 4;
            BU ah, al, rh, rl;
            ah.u = *((const uint4*)&AhT[m][ku]);
            al.u = *((const uint4*)&AlT[m][ku]);
#pragma unroll
            for (int w = 0; w < 4; ++w) {
                unsigned neg = ah.w[w] & 0x80008000u;
                unsigned msk = (neg >> 15) * 0xFFFFu;   // FFFF per negative half
                rh.w[w] = ah.w[w] & ~msk;
                rl.w[w] = al.w[w] & ~msk;
            }
            accC[mt] = __builtin_amdgcn_mfma_f32_16x16x32_bf16(rh.v, Bch[s].v, accC[mt], 0, 0, 0);
            accC[mt] = __builtin_amdgcn_mfma_f32_16x16x32_bf16(rh.v, Bcl[s].v, accC[mt], 0, 0, 0);
            accC[mt] = __builtin_amdgcn_mfma_f32_16x16x32_bf16(rl.v, Bch[s].v, accC[mt], 0, 0, 0);
            accG[mt] = __builtin_amdgcn_mfma_f32_16x16x32_bf16(ah.v, Bgh[s].v, accG[mt], 0, 0, 0);
            accG[mt] = __builtin_amdgcn_mfma_f32_16x16x32_bf16(ah.v, Bgl[s].v, accG[mt], 0, 0, 0);
            accG[mt] = __builtin_amdgcn_mfma_f32_16x16x32_bf16(al.v, Bgh[s].v, accG[mt], 0, 0, 0);
        }
    }

    // ---- epilogue: C/D layout col = l15, row = 4*quad + r; residual from LDS
#pragma unroll
    for (int mt = 0; mt < 4; ++mt) {
        int rbase = mt * 16 + quad * 4;
#pragma unroll
        for (int r = 0; r < 4; ++r) {
            size_t idx = (m0 + rbase + r) * NC + ncol;
            float p = Afp32[rbase + r][ncol];
            Zout[idx] = p + ALPHA_F * accC[mt][r];
            Y2out[idx] = accG[mt][r];
        }
    }
}

// ---------------------------------------------------------------------------
// Aggregate (used once, after the 4th GCN block): P5 = Z + OMA*((Y2+sum)/8)
// ---------------------------------------------------------------------------
__global__ __launch_bounds__(256) void agg_kernel(const float* __restrict__ Z,
                                                  const float* __restrict__ Y2,
                                                  const int* __restrict__ nbr,
                                                  float* __restrict__ Pout) {
    int tid = threadIdx.x;
    int lane = tid & 31, rl = tid >> 5;
    size_t row = (size_t)blockIdx.x * 8 + rl;
    int b = (int)(row >> 11);
    const int* nb = nbr + row * 7;
    size_t off = row * NC + lane * 4;
    float4 ys = *((const float4*)(Y2 + off));
    size_t bbase = (size_t)b * NP * NC;
#pragma unroll
    for (int t = 0; t < 7; ++t) {
        int j = nb[t];
        float4 v = *((const float4*)(Y2 + bbase + (size_t)j * NC + lane * 4));
        ys.x += v.x; ys.y += v.y; ys.z += v.z; ys.w += v.w;
    }
    float4 z = *((const float4*)(Z + off));
    float4 o;
    o.x = OMA_F * (0.125f * ys.x) + z.x;
    o.y = OMA_F * (0.125f * ys.y) + z.y;
    o.z = OMA_F * (0.125f * ys.z) + z.z;
    o.w = OMA_F * (0.125f * ys.w) + z.w;
    *((float4*)(Pout + off)) = o;
}

// ---------------------------------------------------------------------------
// Final small GEMMs: U1 = P @ Wuc^T (6), U2 = P @ Wug^T (6); U row = [U1|U2]
// ---------------------------------------------------------------------------
__global__ __launch_bounds__(256) void final_gemm_kernel(const float* __restrict__ P,
                                                         const float* __restrict__ Wuc,
                                                         const float* __restrict__ Wug,
                                                         float* __restrict__ U) {
    __shared__ float s1[6 * NC], s2[6 * NC];
    for (int m = threadIdx.x; m < 6 * NC; m += 256) { s1[m] = Wuc[m]; s2[m] = Wug[m]; }
    __syncthreads();
    size_t row = (size_t)blockIdx.x * 256 + threadIdx.x;
    const float4* prow = (const float4*)(P + row * NC);
    float a1[6] = {0, 0, 0, 0, 0, 0}, a2[6] = {0, 0, 0, 0, 0, 0};
#pragma unroll 4
    for (int c4 = 0; c4 < NC / 4; ++c4) {
        float4 p = prow[c4];
#pragma unroll
        for (int o = 0; o < 6; ++o) {
            float4 w1 = *((const float4*)&s1[o * NC + c4 * 4]);
            float4 w2 = *((const float4*)&s2[o * NC + c4 * 4]);
            a1[o] += p.x * w1.x + p.y * w1.y + p.z * w1.z + p.w * w1.w;
            a2[o] += p.x * w2.x + p.y * w2.y + p.z * w2.z + p.w * w2.w;
        }
    }
#pragma unroll
    for (int o = 0; o < 6; ++o) {
        U[row * 12 + o] = a1[o];
        U[row * 12 + 6 + o] = a2[o];
    }
}

// ---------------------------------------------------------------------------
// Final output: new_xyz
// ---------------------------------------------------------------------------
__global__ __launch_bounds__(256) void final_out_kernel(const float* __restrict__ U,
                                                        const int* __restrict__ nbr,
                                                        const float* __restrict__ xyz,
                                                        float* __restrict__ out) {
    size_t row = (size_t)blockIdx.x * 256 + threadIdx.x;
    int b = (int)(row >> 11), n = (int)(row & 2047);
    const int* nb = nbr + row * 7;
    float u1[6], u2[6];
#pragma unroll
    for (int o = 0; o < 6; ++o) { u1[o] = U[row * 12 + o]; u2[o] = U[row * 12 + 6 + o]; }
#pragma unroll
    for (int t = 0; t < 7; ++t) {
        int j = nb[t];
        const float* Uj = U + ((size_t)b * NP + j) * 12 + 6;
#pragma unroll
        for (int o = 0; o < 6; ++o) u2[o] += Uj[o];
    }
#pragma unroll
    for (int c = 0; c < 3; ++c)
#pragma unroll
        for (int s = 0; s < 2; ++s) {
            int o = c * 2 + s;
            float val = ALPHA_F * u1[o] + OMA_F * (0.125f * u2[o])
                      + xyz[(size_t)b * 3 * NP + (size_t)c * NP + n];
            out[(size_t)b * 3 * 2 * NP + (size_t)c * 2 * NP + (size_t)s * NP + n] = val;
        }
}

// ---------------------------------------------------------------------------
extern "C" void kernel_launch(void* const* d_in, const int* in_sizes, int n_in,
                              void* d_out, int out_size, void* d_ws, size_t ws_size,
                              hipStream_t stream) {
    const float* xyz    = (const float*)d_in[0];  // (16,3,2048)
    const float* points = (const float*)d_in[1];  // (16,128,2048)
    const float* Wc     = (const float*)d_in[2];  // (4,128,128)
    const float* Wg     = (const float*)d_in[3];  // (4,128,128)
    const float* Wuc    = (const float*)d_in[4];  // (6,128)
    const float* Wug    = (const float*)d_in[5];  // (6,128)
    float* out = (float*)d_out;

    char* ws = (char*)d_ws;
    size_t o = 0;
    int* nbr  = (int*)(ws + o);     o += (size_t)NB * NP * 7 * 4;
    float* Za = (float*)(ws + o);   o += (size_t)NB * NP * NC * 4;     // 16 MB
    float* Ya = (float*)(ws + o);   o += (size_t)NB * NP * NC * 4;
    float* Zb = (float*)(ws + o);   o += (size_t)NB * NP * NC * 4;
    float* Yb = (float*)(ws + o);   o += (size_t)NB * NP * NC * 4;
    float* U  = (float*)(ws + o);   o += (size_t)NB * NP * 12 * 4;

    const int GEMM_GRID = NB * NP / 64;   // 512 tiles

    // 1) KNN (must precede gemm#2's gather staging)
    knn_kernel<<<dim3(NP / 64, NB), 256, 0, stream>>>(xyz, nbr);
    // 2) GCN blocks — agg fused into the next block's A-staging
    gemm_fused_kernel<0><<<GEMM_GRID, 512, 0, stream>>>(points, nullptr, nullptr,
        Wc + 0 * NC * NC, Wg + 0 * NC * NC, Za, Ya);
    gemm_fused_kernel<1><<<GEMM_GRID, 512, 0, stream>>>(Za, Ya, nbr,
        Wc + 1 * NC * NC, Wg + 1 * NC * NC, Zb, Yb);
    gemm_fused_kernel<1><<<GEMM_GRID, 512, 0, stream>>>(Zb, Yb, nbr,
        Wc + 2 * NC * NC, Wg + 2 * NC * NC, Za, Ya);
    gemm_fused_kernel<1><<<GEMM_GRID, 512, 0, stream>>>(Za, Ya, nbr,
        Wc + 3 * NC * NC, Wg + 3 * NC * NC, Zb, Yb);
    // 3) last agg -> P5 (reuse Za)
    float* P5 = Za;
    agg_kernel<<<dim3(NB * NP / 8), 256, 0, stream>>>(Zb, Yb, nbr, P5);
    // 4) final small GEMMs
    final_gemm_kernel<<<dim3(NB * NP / 256), 256, 0, stream>>>(P5, Wuc, Wug, U);
    // 5) new_xyz
    final_out_kernel<<<dim3(NB * NP / 256), 256, 0, stream>>>(U, nbr, xyz, out);
    // 6) pts (B,N,C) -> out2 (B,C,N)
    transpose_kernel<<<dim3(NC / 32, NP / 32, NB), dim3(32, 8), 0, stream>>>(
        P5, out + (size_t)NB * 3 * 2 * NP, NP, NC);
}

// Round 9
// 260.523 us; speedup vs baseline: 5.1768x; 1.1881x over previous
//
#include <hip/hip_runtime.h>
#include <hip/hip_bf16.h>

// Problem constants
static constexpr int NB = 16;     // batches
static constexpr int NP = 2048;   // points per batch
static constexpr int NC = 128;    // channels
#define ALPHA_F ((float)(8.0/9.0))
#define OMA_F   ((float)(1.0 - 8.0/9.0))

typedef __attribute__((ext_vector_type(8))) short bfrag;   // 8 bf16 (4 VGPR)
typedef __attribute__((ext_vector_type(4))) float ffrag;   // 4 fp32 acc

union BU { bfrag v; uint4 u; unsigned int w[4]; };

// split two floats into packed bf16 hi pair + bf16 lo pair
__device__ inline void split2(float x, float y, unsigned& hi, unsigned& lo) {
    __hip_bfloat162 h = __float22bfloat162_rn(make_float2(x, y));
    float2 hb = __bfloat1622float2(h);
    __hip_bfloat162 l = __float22bfloat162_rn(make_float2(x - hb.x, y - hb.y));
    __builtin_memcpy(&hi, &h, 4);
    __builtin_memcpy(&lo, &l, 4);
}

// ---------------------------------------------------------------------------
// KNN v4c: grouped two-phase scan via group bitmask.
// 4 threads/point; thread q owns stripe j = 4*jj+q (512 candidates).
// Pass 1: min over each 8-candidate group (~6.5 ops/cand) + branchless top-8
//         of the 64 group-minima (same insert network as proven v3).
// Winning groups -> 64-bit mask (built with unrolled constant indices: no
// dynamic private-array indexing, no 8x code replication).
// Pass 2: walk mask ascending (ctz / clear-lowest), full (d,j) insert over
//         the 8 winning groups (64 candidates).
// Exact: a true top-8 element's group-min <= its distance <= the 8th-smallest
// group-min, so its group is always selected; ascending group order + the
// strict-< stable insert preserves v3's tie semantics.
// ---------------------------------------------------------------------------
__global__ __launch_bounds__(256) void knn_kernel(const float* __restrict__ xyz,
                                                  int* __restrict__ nbr) {
    __shared__ float4 sp[NP];            // 32 KB
    __shared__ float  md[64][33];
    __shared__ int    mi[64][33];
    int b = blockIdx.y;
    const float* X = xyz + (size_t)b * 3 * NP;
    for (int m = threadIdx.x; m < NP; m += 256) {
        float x = X[m], y = X[NP + m], z = X[2 * NP + m];
        sp[m] = make_float4(x, y, z, x * x + y * y + z * z);
    }
    __syncthreads();

    int tid = threadIdx.x;
    int p = tid >> 2;
    int q = tid & 3;
    int base = blockIdx.x * 64;
    int n = base + p;
    float4 me = sp[n];
    float xi = me.x, yi = me.y, zi = me.z, qi = me.w;

    // ---- pass 1: top-8 groups by group-min
    float gd[8]; int gi[8];
#pragma unroll
    for (int t = 0; t < 8; ++t) { gd[t] = 3.4e38f; gi[t] = 0; }
#pragma unroll 1
    for (int g = 0; g < 64; ++g) {
        float gm = 3.4e38f;
#pragma unroll
        for (int i = 0; i < 8; ++i) {
            int j = (g * 8 + i) * 4 + q;
            float4 c4v = sp[j];
            float inner = xi * c4v.x + yi * c4v.y + zi * c4v.z;
            float d = qi + c4v.w - 2.0f * inner;
            gm = fminf(gm, d);
        }
        bool c[8];
#pragma unroll
        for (int t = 0; t < 8; ++t) c[t] = gm < gd[t];
#pragma unroll
        for (int t = 7; t >= 1; --t) {
            gd[t] = c[t - 1] ? gd[t - 1] : (c[t] ? gm : gd[t]);
            gi[t] = c[t - 1] ? gi[t - 1] : (c[t] ? g : gi[t]);
        }
        gd[0] = c[0] ? gm : gd[0];
        gi[0] = c[0] ? g : gi[0];
    }

    // ---- winning groups -> bitmask (gi[t] read with unrolled const index)
    unsigned long long mask = 0ull;
#pragma unroll
    for (int t = 0; t < 8; ++t) mask |= (1ull << gi[t]);

    // ---- pass 2: full insert over winning groups, ascending group order
    float bd[8]; int bi[8];
#pragma unroll
    for (int t = 0; t < 8; ++t) { bd[t] = 3.4e38f; bi[t] = 0; }
    while (mask) {
        int g = (int)__builtin_ctzll(mask);
        mask &= (mask - 1ull);
#pragma unroll
        for (int i = 0; i < 8; ++i) {
            int j = (g * 8 + i) * 4 + q;
            float4 c4v = sp[j];
            float inner = xi * c4v.x + yi * c4v.y + zi * c4v.z;
            float d = qi + c4v.w - 2.0f * inner;
            bool c[8];
#pragma unroll
            for (int t = 0; t < 8; ++t) c[t] = d < bd[t];
#pragma unroll
            for (int t = 7; t >= 1; --t) {
                bd[t] = c[t - 1] ? bd[t - 1] : (c[t] ? d : bd[t]);
                bi[t] = c[t - 1] ? bi[t - 1] : (c[t] ? j : bi[t]);
            }
            bd[0] = c[0] ? d : bd[0];
            bi[0] = c[0] ? j : bi[0];
        }
    }
#pragma unroll
    for (int t = 0; t < 8; ++t) {
        md[p][q * 8 + t] = bd[t];
        mi[p][q * 8 + t] = bi[t];
    }
    __syncthreads();

    if (tid < 64) {
        float fd[8]; int fi[8];
#pragma unroll
        for (int t = 0; t < 8; ++t) { fd[t] = 3.4e38f; fi[t] = 0; }
#pragma unroll 4
        for (int cc = 0; cc < 32; ++cc) {
            float d = md[tid][cc];
            int j = mi[tid][cc];
            bool c[8];
#pragma unroll
            for (int t = 0; t < 8; ++t) c[t] = d < fd[t];
#pragma unroll
            for (int t = 7; t >= 1; --t) {
                fd[t] = c[t - 1] ? fd[t - 1] : (c[t] ? d : fd[t]);
                fi[t] = c[t - 1] ? fi[t - 1] : (c[t] ? j : fi[t]);
            }
            fd[0] = c[0] ? d : fd[0];
            fi[0] = c[0] ? j : fi[0];
        }
        int row = b * NP + base + tid;
#pragma unroll
        for (int t = 0; t < 7; ++t) nbr[row * 7 + t] = fi[t + 1];
    }
}

// ---------------------------------------------------------------------------
// Generic batched transpose of last two dims: in (B,R,S) -> out (B,S,R)
// (round-5 version, known good)
// ---------------------------------------------------------------------------
__global__ __launch_bounds__(256) void transpose_kernel(const float* __restrict__ in,
                                                        float* __restrict__ out,
                                                        int R, int S) {
    __shared__ float t[32][33];
    int b = blockIdx.z;
    int s0 = blockIdx.x * 32, r0 = blockIdx.y * 32;
    const float* I = in + (size_t)b * R * S;
    float* O = out + (size_t)b * R * S;
#pragma unroll
    for (int i = 0; i < 4; ++i) {
        int r = r0 + threadIdx.y + i * 8;
        t[threadIdx.y + i * 8][threadIdx.x] = I[(size_t)r * S + s0 + threadIdx.x];
    }
    __syncthreads();
#pragma unroll
    for (int i = 0; i < 4; ++i) {
        int s = s0 + threadIdx.y + i * 8;
        O[(size_t)s * R + r0 + threadIdx.x] = t[threadIdx.x][threadIdx.y + i * 8];
    }
}

// ---------------------------------------------------------------------------
// Fused GCN block (round-5 version, known good):
//   MODE 0: A = points^T tile (transpose fused)
//   MODE 1: A = Zprev + (1-ALPHA)*((Y2prev[self] + sum_nbr Y2prev)/8)
//   Outputs: Zout = A + ALPHA*(relu(A) @ Wc^T) ;  Y2out = A @ Wg^T
// ---------------------------------------------------------------------------
template <int MODE>
__global__ __launch_bounds__(512) void gemm_fused_kernel(const float* __restrict__ Asrc,
                                                         const float* __restrict__ Y2in,
                                                         const int* __restrict__ nbr,
                                                         const float* __restrict__ Wc,
                                                         const float* __restrict__ Wg,
                                                         float* __restrict__ Zout,
                                                         float* __restrict__ Y2out) {
    __shared__ float Afp32[64][132];       // 33.8 KB (fp32 A tile, stride 132)
    __shared__ unsigned int AhT[64][68];   // 17.4 KB
    __shared__ unsigned int AlT[64][68];   // 17.4 KB
    __shared__ int s_nb[448];              // 1.75 KB
    int tid = threadIdx.x;
    int wid = tid >> 6, lane = tid & 63;
    int quad = lane >> 4, l15 = lane & 15;
    int bb = blockIdx.x >> 5;
    int n0 = (blockIdx.x & 31) << 6;
    size_t m0 = (size_t)bb * NP + n0;

    // ---- stage A tile (fp32) into LDS
    if (MODE == 1) {
        if (tid < 448) s_nb[tid] = nbr[m0 * 7 + tid];
        __syncthreads();
        size_t bbase = (size_t)bb * NP;
#pragma unroll 1
        for (int it = 0; it < 4; ++it) {
            int f = tid + it * 512;
            int r = f >> 5, c4 = (f & 31) * 4;
            size_t row = m0 + r;
            float4 z = *((const float4*)(Asrc + row * NC + c4));
            float4 acc = *((const float4*)(Y2in + row * NC + c4));
#pragma unroll
            for (int t = 0; t < 7; ++t) {
                int j = s_nb[r * 7 + t];
                float4 v = *((const float4*)(Y2in + (bbase + (size_t)j) * NC + c4));
                acc.x += v.x; acc.y += v.y; acc.z += v.z; acc.w += v.w;
            }
            float4 a;
            a.x = OMA_F * (0.125f * acc.x) + z.x;
            a.y = OMA_F * (0.125f * acc.y) + z.y;
            a.z = OMA_F * (0.125f * acc.z) + z.z;
            a.w = OMA_F * (0.125f * acc.w) + z.w;
            *((float4*)&Afp32[r][c4]) = a;
        }
    } else {
        // A[r][c] = points[b][c][n0+r]
#pragma unroll
        for (int it = 0; it < 4; ++it) {
            int f = tid + it * 512;
            int c = f >> 4, rq = (f & 15) * 4;
            float4 v = *((const float4*)(Asrc + ((size_t)bb * NC + c) * NP + n0 + rq));
            Afp32[rq][c] = v.x; Afp32[rq + 1][c] = v.y;
            Afp32[rq + 2][c] = v.z; Afp32[rq + 3][c] = v.w;
        }
    }

    // ---- B-frags (W loads overlap the staging barrier)
    int ncol = wid * 16 + l15;
    const float* wcr = Wc + (size_t)ncol * NC + quad * 8;
    const float* wgr = Wg + (size_t)ncol * NC + quad * 8;
    BU Bch[4], Bcl[4], Bgh[4], Bgl[4];
#pragma unroll
    for (int s = 0; s < 4; ++s) {
        float4 c0 = *((const float4*)(wcr + s * 32));
        float4 c1 = *((const float4*)(wcr + s * 32 + 4));
        split2(c0.x, c0.y, Bch[s].w[0], Bcl[s].w[0]);
        split2(c0.z, c0.w, Bch[s].w[1], Bcl[s].w[1]);
        split2(c1.x, c1.y, Bch[s].w[2], Bcl[s].w[2]);
        split2(c1.z, c1.w, Bch[s].w[3], Bcl[s].w[3]);
        float4 g0 = *((const float4*)(wgr + s * 32));
        float4 g1 = *((const float4*)(wgr + s * 32 + 4));
        split2(g0.x, g0.y, Bgh[s].w[0], Bgl[s].w[0]);
        split2(g0.z, g0.w, Bgh[s].w[1], Bgl[s].w[1]);
        split2(g1.x, g1.y, Bgh[s].w[2], Bgl[s].w[2]);
        split2(g1.z, g1.w, Bgh[s].w[3], Bgl[s].w[3]);
    }
    __syncthreads();

    // ---- split A into bf16 hi/lo planes
#pragma unroll
    for (int it = 0; it < 4; ++it) {
        int f = tid + it * 512;
        int r = f >> 5, c4 = (f & 31) * 4;
        float4 v = *((const float4*)&Afp32[r][c4]);
        unsigned h01, l01, h23, l23;
        split2(v.x, v.y, h01, l01);
        split2(v.z, v.w, h23, l23);
        *((uint2*)&AhT[r][c4 >> 1]) = make_uint2(h01, h23);
        *((uint2*)&AlT[r][c4 >> 1]) = make_uint2(l01, l23);
    }
    __syncthreads();

    ffrag accC[4], accG[4];
#pragma unroll
    for (int mt = 0; mt < 4; ++mt) { accC[mt] = (ffrag)0.0f; accG[mt] = (ffrag)0.0f; }

#pragma unroll
    for (int s = 0; s < 4; ++s) {
#pragma unroll
        for (int mt = 0; mt < 4; ++mt) {
            int m = mt * 16 + l15;
            int ku = s * 16 + quad * 4;
            BU ah, al, rh, rl;
            ah.u = *((const uint4*)&AhT[m][ku]);
            al.u = *((const uint4*)&AlT[m][ku]);
#pragma unroll
            for (int w = 0; w < 4; ++w) {
                unsigned msk = ((ah.w[w] & 0x80008000u) >> 15) * 0xFFFFu;
                rh.w[w] = ah.w[w] & ~msk;
                rl.w[w] = al.w[w] & ~msk;
            }
            accC[mt] = __builtin_amdgcn_mfma_f32_16x16x32_bf16(rh.v, Bch[s].v, accC[mt], 0, 0, 0);
            accC[mt] = __builtin_amdgcn_mfma_f32_16x16x32_bf16(rh.v, Bcl[s].v, accC[mt], 0, 0, 0);
            accC[mt] = __builtin_amdgcn_mfma_f32_16x16x32_bf16(rl.v, Bch[s].v, accC[mt], 0, 0, 0);
            accG[mt] = __builtin_amdgcn_mfma_f32_16x16x32_bf16(ah.v, Bgh[s].v, accG[mt], 0, 0, 0);
            accG[mt] = __builtin_amdgcn_mfma_f32_16x16x32_bf16(ah.v, Bgl[s].v, accG[mt], 0, 0, 0);
            accG[mt] = __builtin_amdgcn_mfma_f32_16x16x32_bf16(al.v, Bgh[s].v, accG[mt], 0, 0, 0);
        }
    }

    // ---- epilogue: col = l15, row = 4*quad + r; residual from fp32 LDS
#pragma unroll
    for (int mt = 0; mt < 4; ++mt) {
        int rbase = mt * 16 + quad * 4;
#pragma unroll
        for (int r = 0; r < 4; ++r) {
            size_t idx = (m0 + rbase + r) * NC + ncol;
            float p = Afp32[rbase + r][ncol];
            Zout[idx] = p + ALPHA_F * accC[mt][r];
            Y2out[idx] = accG[mt][r];
        }
    }
}

// ---------------------------------------------------------------------------
// Aggregate (round-5 version, known good): P5 = Z + OMA*((Y2+sum)/8)
// ---------------------------------------------------------------------------
__global__ __launch_bounds__(256) void agg_kernel(const float* __restrict__ Z,
                                                  const float* __restrict__ Y2,
                                                  const int* __restrict__ nbr,
                                                  float* __restrict__ Pout) {
    int tid = threadIdx.x;
    int lane = tid & 31, rl = tid >> 5;
    size_t row = (size_t)blockIdx.x * 8 + rl;
    int b = (int)(row >> 11);
    const int* nb = nbr + row * 7;
    size_t off = row * NC + lane * 4;
    float4 ys = *((const float4*)(Y2 + off));
    size_t bbase = (size_t)b * NP * NC;
#pragma unroll
    for (int t = 0; t < 7; ++t) {
        int j = nb[t];
        float4 v = *((const float4*)(Y2 + bbase + (size_t)j * NC + lane * 4));
        ys.x += v.x; ys.y += v.y; ys.z += v.z; ys.w += v.w;
    }
    float4 z = *((const float4*)(Z + off));
    float4 o;
    o.x = OMA_F * (0.125f * ys.x) + z.x;
    o.y = OMA_F * (0.125f * ys.y) + z.y;
    o.z = OMA_F * (0.125f * ys.z) + z.z;
    o.w = OMA_F * (0.125f * ys.w) + z.w;
    *((float4*)(Pout + off)) = o;
}

// ---------------------------------------------------------------------------
// Final small GEMMs: U1 = P @ Wuc^T (6), U2 = P @ Wug^T (6); U row = [U1|U2]
// ---------------------------------------------------------------------------
__global__ __launch_bounds__(256) void final_gemm_kernel(const float* __restrict__ P,
                                                         const float* __restrict__ Wuc,
                                                         const float* __restrict__ Wug,
                                                         float* __restrict__ U) {
    __shared__ float s1[6 * NC], s2[6 * NC];
    for (int m = threadIdx.x; m < 6 * NC; m += 256) { s1[m] = Wuc[m]; s2[m] = Wug[m]; }
    __syncthreads();
    size_t row = (size_t)blockIdx.x * 256 + threadIdx.x;
    const float4* prow = (const float4*)(P + row * NC);
    float a1[6] = {0, 0, 0, 0, 0, 0}, a2[6] = {0, 0, 0, 0, 0, 0};
#pragma unroll 4
    for (int c4 = 0; c4 < NC / 4; ++c4) {
        float4 p = prow[c4];
#pragma unroll
        for (int o = 0; o < 6; ++o) {
            float4 w1 = *((const float4*)&s1[o * NC + c4 * 4]);
            float4 w2 = *((const float4*)&s2[o * NC + c4 * 4]);
            a1[o] += p.x * w1.x + p.y * w1.y + p.z * w1.z + p.w * w1.w;
            a2[o] += p.x * w2.x + p.y * w2.y + p.z * w2.z + p.w * w2.w;
        }
    }
#pragma unroll
    for (int o = 0; o < 6; ++o) {
        U[row * 12 + o] = a1[o];
        U[row * 12 + 6 + o] = a2[o];
    }
}

// ---------------------------------------------------------------------------
// Final output: new_xyz
// ---------------------------------------------------------------------------
__global__ __launch_bounds__(256) void final_out_kernel(const float* __restrict__ U,
                                                        const int* __restrict__ nbr,
                                                        const float* __restrict__ xyz,
                                                        float* __restrict__ out) {
    size_t row = (size_t)blockIdx.x * 256 + threadIdx.x;
    int b = (int)(row >> 11), n = (int)(row & 2047);
    const int* nb = nbr + row * 7;
    float u1[6], u2[6];
#pragma unroll
    for (int o = 0; o < 6; ++o) { u1[o] = U[row * 12 + o]; u2[o] = U[row * 12 + 6 + o]; }
#pragma unroll
    for (int t = 0; t < 7; ++t) {
        int j = nb[t];
        const float* Uj = U + ((size_t)b * NP + j) * 12 + 6;
#pragma unroll
        for (int o = 0; o < 6; ++o) u2[o] += Uj[o];
    }
#pragma unroll
    for (int c = 0; c < 3; ++c)
#pragma unroll
        for (int s = 0; s < 2; ++s) {
            int o = c * 2 + s;
            float val = ALPHA_F * u1[o] + OMA_F * (0.125f * u2[o])
                      + xyz[(size_t)b * 3 * NP + (size_t)c * NP + n];
            out[(size_t)b * 3 * 2 * NP + (size_t)c * 2 * NP + (size_t)s * NP + n] = val;
        }
}

// ---------------------------------------------------------------------------
extern "C" void kernel_launch(void* const* d_in, const int* in_sizes, int n_in,
                              void* d_out, int out_size, void* d_ws, size_t ws_size,
                              hipStream_t stream) {
    const float* xyz    = (const float*)d_in[0];  // (16,3,2048)
    const float* points = (const float*)d_in[1];  // (16,128,2048)
    const float* Wc     = (const float*)d_in[2];  // (4,128,128)
    const float* Wg     = (const float*)d_in[3];  // (4,128,128)
    const float* Wuc    = (const float*)d_in[4];  // (6,128)
    const float* Wug    = (const float*)d_in[5];  // (6,128)
    float* out = (float*)d_out;

    char* ws = (char*)d_ws;
    size_t o = 0;
    int* nbr  = (int*)(ws + o);     o += (size_t)NB * NP * 7 * 4;
    float* Za = (float*)(ws + o);   o += (size_t)NB * NP * NC * 4;     // 16 MB
    float* Ya = (float*)(ws + o);   o += (size_t)NB * NP * NC * 4;
    float* Zb = (float*)(ws + o);   o += (size_t)NB * NP * NC * 4;
    float* Yb = (float*)(ws + o);   o += (size_t)NB * NP * NC * 4;
    float* U  = (float*)(ws + o);   o += (size_t)NB * NP * 12 * 4;

    const int GEMM_GRID = NB * NP / 64;   // 512 tiles

    // 1) KNN
    knn_kernel<<<dim3(NP / 64, NB), 256, 0, stream>>>(xyz, nbr);
    // 2) GCN blocks — agg fused into next block's A-staging
    gemm_fused_kernel<0><<<GEMM_GRID, 512, 0, stream>>>(points, nullptr, nullptr,
        Wc + 0 * NC * NC, Wg + 0 * NC * NC, Za, Ya);
    gemm_fused_kernel<1><<<GEMM_GRID, 512, 0, stream>>>(Za, Ya, nbr,
        Wc + 1 * NC * NC, Wg + 1 * NC * NC, Zb, Yb);
    gemm_fused_kernel<1><<<GEMM_GRID, 512, 0, stream>>>(Zb, Yb, nbr,
        Wc + 2 * NC * NC, Wg + 2 * NC * NC, Za, Ya);
    gemm_fused_kernel<1><<<GEMM_GRID, 512, 0, stream>>>(Za, Ya, nbr,
        Wc + 3 * NC * NC, Wg + 3 * NC * NC, Zb, Yb);
    // 3) last agg -> P5 (reuse Za)
    float* P5 = Za;
    agg_kernel<<<dim3(NB * NP / 8), 256, 0, stream>>>(Zb, Yb, nbr, P5);
    // 4) final small GEMMs
    final_gemm_kernel<<<dim3(NB * NP / 256), 256, 0, stream>>>(P5, Wuc, Wug, U);
    // 5) new_xyz
    final_out_kernel<<<dim3(NB * NP / 256), 256, 0, stream>>>(U, nbr, xyz, out);
    // 6) pts (B,N,C) -> out2 (B,C,N)
    transpose_kernel<<<dim3(NC / 32, NP / 32, NB), dim3(32, 8), 0, stream>>>(
        P5, out + (size_t)NB * 3 * 2 * NP, NP, NC);
}

// Round 10
// 258.064 us; speedup vs baseline: 5.2261x; 1.0095x over previous
//
#include <hip/hip_runtime.h>
#include <hip/hip_bf16.h>

// Problem constants
static constexpr int NB = 16;     // batches
static constexpr int NP = 2048;   // points per batch
static constexpr int NC = 128;    // channels
#define ALPHA_F ((float)(8.0/9.0))
#define OMA_F   ((float)(1.0 - 8.0/9.0))

typedef __attribute__((ext_vector_type(8))) short bfrag;   // 8 bf16 (4 VGPR)
typedef __attribute__((ext_vector_type(4))) float ffrag;   // 4 fp32 acc

union BU { bfrag v; uint4 u; unsigned int w[4]; };

// split two floats into packed bf16 hi pair + bf16 lo pair
__device__ inline void split2(float x, float y, unsigned& hi, unsigned& lo) {
    __hip_bfloat162 h = __float22bfloat162_rn(make_float2(x, y));
    float2 hb = __bfloat1622float2(h);
    __hip_bfloat162 l = __float22bfloat162_rn(make_float2(x - hb.x, y - hb.y));
    __builtin_memcpy(&hi, &h, 4);
    __builtin_memcpy(&lo, &l, 4);
}

__device__ inline void split1(float x, unsigned short& h, unsigned short& l) {
    __hip_bfloat16 hb = __float2bfloat16(x);
    float hf = __bfloat162float(hb);
    __hip_bfloat16 lb = __float2bfloat16(x - hf);
    __builtin_memcpy(&h, &hb, 2);
    __builtin_memcpy(&l, &lb, 2);
}

// ---------------------------------------------------------------------------
// KNN v4c (round-9, green): grouped two-phase scan via group bitmask.
// ---------------------------------------------------------------------------
__global__ __launch_bounds__(256) void knn_kernel(const float* __restrict__ xyz,
                                                  int* __restrict__ nbr) {
    __shared__ float4 sp[NP];            // 32 KB
    __shared__ float  md[64][33];
    __shared__ int    mi[64][33];
    int b = blockIdx.y;
    const float* X = xyz + (size_t)b * 3 * NP;
    for (int m = threadIdx.x; m < NP; m += 256) {
        float x = X[m], y = X[NP + m], z = X[2 * NP + m];
        sp[m] = make_float4(x, y, z, x * x + y * y + z * z);
    }
    __syncthreads();

    int tid = threadIdx.x;
    int p = tid >> 2;
    int q = tid & 3;
    int base = blockIdx.x * 64;
    int n = base + p;
    float4 me = sp[n];
    float xi = me.x, yi = me.y, zi = me.z, qi = me.w;

    // ---- pass 1: top-8 groups by group-min
    float gd[8]; int gi[8];
#pragma unroll
    for (int t = 0; t < 8; ++t) { gd[t] = 3.4e38f; gi[t] = 0; }
#pragma unroll 1
    for (int g = 0; g < 64; ++g) {
        float gm = 3.4e38f;
#pragma unroll
        for (int i = 0; i < 8; ++i) {
            int j = (g * 8 + i) * 4 + q;
            float4 c4v = sp[j];
            float inner = xi * c4v.x + yi * c4v.y + zi * c4v.z;
            float d = qi + c4v.w - 2.0f * inner;
            gm = fminf(gm, d);
        }
        bool c[8];
#pragma unroll
        for (int t = 0; t < 8; ++t) c[t] = gm < gd[t];
#pragma unroll
        for (int t = 7; t >= 1; --t) {
            gd[t] = c[t - 1] ? gd[t - 1] : (c[t] ? gm : gd[t]);
            gi[t] = c[t - 1] ? gi[t - 1] : (c[t] ? g : gi[t]);
        }
        gd[0] = c[0] ? gm : gd[0];
        gi[0] = c[0] ? g : gi[0];
    }

    unsigned long long mask = 0ull;
#pragma unroll
    for (int t = 0; t < 8; ++t) mask |= (1ull << gi[t]);

    // ---- pass 2: full insert over winning groups, ascending group order
    float bd[8]; int bi[8];
#pragma unroll
    for (int t = 0; t < 8; ++t) { bd[t] = 3.4e38f; bi[t] = 0; }
    while (mask) {
        int g = (int)__builtin_ctzll(mask);
        mask &= (mask - 1ull);
#pragma unroll
        for (int i = 0; i < 8; ++i) {
            int j = (g * 8 + i) * 4 + q;
            float4 c4v = sp[j];
            float inner = xi * c4v.x + yi * c4v.y + zi * c4v.z;
            float d = qi + c4v.w - 2.0f * inner;
            bool c[8];
#pragma unroll
            for (int t = 0; t < 8; ++t) c[t] = d < bd[t];
#pragma unroll
            for (int t = 7; t >= 1; --t) {
                bd[t] = c[t - 1] ? bd[t - 1] : (c[t] ? d : bd[t]);
                bi[t] = c[t - 1] ? bi[t - 1] : (c[t] ? j : bi[t]);
            }
            bd[0] = c[0] ? d : bd[0];
            bi[0] = c[0] ? j : bi[0];
        }
    }
#pragma unroll
    for (int t = 0; t < 8; ++t) {
        md[p][q * 8 + t] = bd[t];
        mi[p][q * 8 + t] = bi[t];
    }
    __syncthreads();

    if (tid < 64) {
        float fd[8]; int fi[8];
#pragma unroll
        for (int t = 0; t < 8; ++t) { fd[t] = 3.4e38f; fi[t] = 0; }
#pragma unroll 4
        for (int cc = 0; cc < 32; ++cc) {
            float d = md[tid][cc];
            int j = mi[tid][cc];
            bool c[8];
#pragma unroll
            for (int t = 0; t < 8; ++t) c[t] = d < fd[t];
#pragma unroll
            for (int t = 7; t >= 1; --t) {
                fd[t] = c[t - 1] ? fd[t - 1] : (c[t] ? d : fd[t]);
                fi[t] = c[t - 1] ? fi[t - 1] : (c[t] ? j : fi[t]);
            }
            fd[0] = c[0] ? d : fd[0];
            fi[0] = c[0] ? j : fi[0];
        }
        int row = b * NP + base + tid;
#pragma unroll
        for (int t = 0; t < 7; ++t) nbr[row * 7 + t] = fi[t + 1];
    }
}

// ---------------------------------------------------------------------------
// Generic batched transpose of last two dims: in (B,R,S) -> out (B,S,R)
// ---------------------------------------------------------------------------
__global__ __launch_bounds__(256) void transpose_kernel(const float* __restrict__ in,
                                                        float* __restrict__ out,
                                                        int R, int S) {
    __shared__ float t[32][33];
    int b = blockIdx.z;
    int s0 = blockIdx.x * 32, r0 = blockIdx.y * 32;
    const float* I = in + (size_t)b * R * S;
    float* O = out + (size_t)b * R * S;
#pragma unroll
    for (int i = 0; i < 4; ++i) {
        int r = r0 + threadIdx.y + i * 8;
        t[threadIdx.y + i * 8][threadIdx.x] = I[(size_t)r * S + s0 + threadIdx.x];
    }
    __syncthreads();
#pragma unroll
    for (int i = 0; i < 4; ++i) {
        int s = s0 + threadIdx.y + i * 8;
        O[(size_t)s * R + r0 + threadIdx.x] = t[threadIdx.x][threadIdx.y + i * 8];
    }
}

// ---------------------------------------------------------------------------
// Pre-split W into MFMA-frag-ordered bf16 hi/lo uint4 pairs (one-time).
// Slot t = layer<<12 | mat<<11 | s<<9 | quad<<7 | ncol -> WP[t*2] = hi,
// WP[t*2+1] = lo, covering W[ncol][s*32+quad*8 .. +8].
// ---------------------------------------------------------------------------
__global__ __launch_bounds__(256) void prep_w_kernel(const float* __restrict__ Wc,
                                                     const float* __restrict__ Wg,
                                                     uint4* __restrict__ WP) {
    int t = blockIdx.x * 256 + threadIdx.x;
    int ncol = t & 127;
    int quad = (t >> 7) & 3;
    int s = (t >> 9) & 3;
    int mat = (t >> 11) & 1;
    int layer = t >> 12;
    const float* W = (mat ? Wg : Wc) + (size_t)layer * NC * NC + (size_t)ncol * NC + s * 32 + quad * 8;
    float4 a = *((const float4*)W);
    float4 b = *((const float4*)(W + 4));
    BU hi, lo;
    split2(a.x, a.y, hi.w[0], lo.w[0]);
    split2(a.z, a.w, hi.w[1], lo.w[1]);
    split2(b.x, b.y, hi.w[2], lo.w[2]);
    split2(b.z, b.w, hi.w[3], lo.w[3]);
    WP[t * 2] = hi.u;
    WP[t * 2 + 1] = lo.u;
}

// ---------------------------------------------------------------------------
// Fused GCN block v2 (MFMA split-bf16, pre-split W, inline A split):
//   MODE 0: A = points^T tile (transpose fused)
//   MODE 1: A = Zprev + (1-ALPHA)*((Y2prev[self] + sum_nbr Y2prev)/8)
//   Outputs: Zout = A + ALPHA*(relu(A) @ Wc^T) ;  Y2out = A @ Wg^T
// A staged directly as two bf16 ushort planes [64][136] (byte-identical
// banking to the proven [64][68] uint layout); relu derived from hi sign
// bits; epilogue residual = hi+lo (rel err ~2^-17).
// LDS 36.6 KB -> 4 blocks/CU.
// ---------------------------------------------------------------------------
template <int MODE>
__global__ __launch_bounds__(512) void gemm_fused_kernel(const float* __restrict__ Asrc,
                                                         const float* __restrict__ Y2in,
                                                         const int* __restrict__ nbr,
                                                         const uint4* __restrict__ WPc,
                                                         const uint4* __restrict__ WPg,
                                                         float* __restrict__ Zout,
                                                         float* __restrict__ Y2out) {
    __shared__ unsigned short AhT[64][136];   // 17.4 KB
    __shared__ unsigned short AlT[64][136];   // 17.4 KB
    __shared__ int s_nb[448];
    int tid = threadIdx.x;
    int wid = tid >> 6, lane = tid & 63;
    int quad = lane >> 4, l15 = lane & 15;
    int bb = blockIdx.x >> 5;
    int n0 = (blockIdx.x & 31) << 6;
    size_t m0 = (size_t)bb * NP + n0;
    int ncol = wid * 16 + l15;

    // ---- W frags: pre-split, frag-ordered; 16 L2-hot b128 loads, zero VALU
    BU Bch[4], Bcl[4], Bgh[4], Bgl[4];
#pragma unroll
    for (int s = 0; s < 4; ++s) {
        int idx = ((s * 4 + quad) * 128 + ncol) * 2;
        Bch[s].u = WPc[idx];
        Bcl[s].u = WPc[idx + 1];
        Bgh[s].u = WPg[idx];
        Bgl[s].u = WPg[idx + 1];
    }

    // ---- stage A tile, splitting to bf16 planes inline
    if (MODE == 1) {
        if (tid < 448) s_nb[tid] = nbr[m0 * 7 + tid];
        __syncthreads();
        size_t bbase = (size_t)bb * NP;
#pragma unroll 1
        for (int it = 0; it < 4; ++it) {
            int f = tid + it * 512;
            int r = f >> 5, c4 = (f & 31) * 4;
            size_t row = m0 + r;
            float4 z = *((const float4*)(Asrc + row * NC + c4));
            float4 acc = *((const float4*)(Y2in + row * NC + c4));
#pragma unroll
            for (int t = 0; t < 7; ++t) {
                int j = s_nb[r * 7 + t];
                float4 v = *((const float4*)(Y2in + (bbase + (size_t)j) * NC + c4));
                acc.x += v.x; acc.y += v.y; acc.z += v.z; acc.w += v.w;
            }
            float4 a;
            a.x = OMA_F * (0.125f * acc.x) + z.x;
            a.y = OMA_F * (0.125f * acc.y) + z.y;
            a.z = OMA_F * (0.125f * acc.z) + z.z;
            a.w = OMA_F * (0.125f * acc.w) + z.w;
            unsigned h01, l01, h23, l23;
            split2(a.x, a.y, h01, l01);
            split2(a.z, a.w, h23, l23);
            *((uint2*)&AhT[r][c4]) = make_uint2(h01, h23);
            *((uint2*)&AlT[r][c4]) = make_uint2(l01, l23);
        }
    } else {
        // A[r][c] = points[b][c][n0+r]: float4 along n, split scalar, b16 writes
#pragma unroll
        for (int it = 0; it < 4; ++it) {
            int f = tid + it * 512;
            int c = f >> 4, rq = (f & 15) * 4;
            float4 v = *((const float4*)(Asrc + ((size_t)bb * NC + c) * NP + n0 + rq));
            float vv[4] = {v.x, v.y, v.z, v.w};
#pragma unroll
            for (int k = 0; k < 4; ++k) {
                unsigned short h, l;
                split1(vv[k], h, l);
                AhT[rq + k][c] = h;
                AlT[rq + k][c] = l;
            }
        }
    }
    __syncthreads();

    ffrag accC[4], accG[4];
#pragma unroll
    for (int mt = 0; mt < 4; ++mt) { accC[mt] = (ffrag)0.0f; accG[mt] = (ffrag)0.0f; }

#pragma unroll
    for (int s = 0; s < 4; ++s) {
#pragma unroll
        for (int mt = 0; mt < 4; ++mt) {
            int m = mt * 16 + l15;
            int k = s * 32 + quad * 8;
            BU ah, al, rh, rl;
            ah.u = *((const uint4*)&AhT[m][k]);
            al.u = *((const uint4*)&AlT[m][k]);
#pragma unroll
            for (int w = 0; w < 4; ++w) {
                unsigned msk = ((ah.w[w] & 0x80008000u) >> 15) * 0xFFFFu;
                rh.w[w] = ah.w[w] & ~msk;
                rl.w[w] = al.w[w] & ~msk;
            }
            accC[mt] = __builtin_amdgcn_mfma_f32_16x16x32_bf16(rh.v, Bch[s].v, accC[mt], 0, 0, 0);
            accC[mt] = __builtin_amdgcn_mfma_f32_16x16x32_bf16(rh.v, Bcl[s].v, accC[mt], 0, 0, 0);
            accC[mt] = __builtin_amdgcn_mfma_f32_16x16x32_bf16(rl.v, Bch[s].v, accC[mt], 0, 0, 0);
            accG[mt] = __builtin_amdgcn_mfma_f32_16x16x32_bf16(ah.v, Bgh[s].v, accG[mt], 0, 0, 0);
            accG[mt] = __builtin_amdgcn_mfma_f32_16x16x32_bf16(ah.v, Bgl[s].v, accG[mt], 0, 0, 0);
            accG[mt] = __builtin_amdgcn_mfma_f32_16x16x32_bf16(al.v, Bgh[s].v, accG[mt], 0, 0, 0);
        }
    }

    // ---- epilogue: col = l15, row = 4*quad + r; residual p = hi + lo
#pragma unroll
    for (int mt = 0; mt < 4; ++mt) {
        int rbase = mt * 16 + quad * 4;
#pragma unroll
        for (int r = 0; r < 4; ++r) {
            int rr = rbase + r;
            unsigned hb = ((unsigned)AhT[rr][ncol]) << 16;
            unsigned lb = ((unsigned)AlT[rr][ncol]) << 16;
            float hp, lp;
            __builtin_memcpy(&hp, &hb, 4);
            __builtin_memcpy(&lp, &lb, 4);
            float p = hp + lp;
            size_t idx = (m0 + rr) * NC + ncol;
            Zout[idx] = p + ALPHA_F * accC[mt][r];
            Y2out[idx] = accG[mt][r];
        }
    }
}

// ---------------------------------------------------------------------------
// Aggregate (round-5 version, known good): P5 = Z + OMA*((Y2+sum)/8)
// ---------------------------------------------------------------------------
__global__ __launch_bounds__(256) void agg_kernel(const float* __restrict__ Z,
                                                  const float* __restrict__ Y2,
                                                  const int* __restrict__ nbr,
                                                  float* __restrict__ Pout) {
    int tid = threadIdx.x;
    int lane = tid & 31, rl = tid >> 5;
    size_t row = (size_t)blockIdx.x * 8 + rl;
    int b = (int)(row >> 11);
    const int* nb = nbr + row * 7;
    size_t off = row * NC + lane * 4;
    float4 ys = *((const float4*)(Y2 + off));
    size_t bbase = (size_t)b * NP * NC;
#pragma unroll
    for (int t = 0; t < 7; ++t) {
        int j = nb[t];
        float4 v = *((const float4*)(Y2 + bbase + (size_t)j * NC + lane * 4));
        ys.x += v.x; ys.y += v.y; ys.z += v.z; ys.w += v.w;
    }
    float4 z = *((const float4*)(Z + off));
    float4 o;
    o.x = OMA_F * (0.125f * ys.x) + z.x;
    o.y = OMA_F * (0.125f * ys.y) + z.y;
    o.z = OMA_F * (0.125f * ys.z) + z.z;
    o.w = OMA_F * (0.125f * ys.w) + z.w;
    *((float4*)(Pout + off)) = o;
}

// ---------------------------------------------------------------------------
// Final small GEMMs: U1 = P @ Wuc^T (6), U2 = P @ Wug^T (6); U row = [U1|U2]
// ---------------------------------------------------------------------------
__global__ __launch_bounds__(256) void final_gemm_kernel(const float* __restrict__ P,
                                                         const float* __restrict__ Wuc,
                                                         const float* __restrict__ Wug,
                                                         float* __restrict__ U) {
    __shared__ float s1[6 * NC], s2[6 * NC];
    for (int m = threadIdx.x; m < 6 * NC; m += 256) { s1[m] = Wuc[m]; s2[m] = Wug[m]; }
    __syncthreads();
    size_t row = (size_t)blockIdx.x * 256 + threadIdx.x;
    const float4* prow = (const float4*)(P + row * NC);
    float a1[6] = {0, 0, 0, 0, 0, 0}, a2[6] = {0, 0, 0, 0, 0, 0};
#pragma unroll 4
    for (int c4 = 0; c4 < NC / 4; ++c4) {
        float4 p = prow[c4];
#pragma unroll
        for (int o = 0; o < 6; ++o) {
            float4 w1 = *((const float4*)&s1[o * NC + c4 * 4]);
            float4 w2 = *((const float4*)&s2[o * NC + c4 * 4]);
            a1[o] += p.x * w1.x + p.y * w1.y + p.z * w1.z + p.w * w1.w;
            a2[o] += p.x * w2.x + p.y * w2.y + p.z * w2.z + p.w * w2.w;
        }
    }
#pragma unroll
    for (int o = 0; o < 6; ++o) {
        U[row * 12 + o] = a1[o];
        U[row * 12 + 6 + o] = a2[o];
    }
}

// ---------------------------------------------------------------------------
// Final output: new_xyz
// ---------------------------------------------------------------------------
__global__ __launch_bounds__(256) void final_out_kernel(const float* __restrict__ U,
                                                        const int* __restrict__ nbr,
                                                        const float* __restrict__ xyz,
                                                        float* __restrict__ out) {
    size_t row = (size_t)blockIdx.x * 256 + threadIdx.x;
    int b = (int)(row >> 11), n = (int)(row & 2047);
    const int* nb = nbr + row * 7;
    float u1[6], u2[6];
#pragma unroll
    for (int o = 0; o < 6; ++o) { u1[o] = U[row * 12 + o]; u2[o] = U[row * 12 + 6 + o]; }
#pragma unroll
    for (int t = 0; t < 7; ++t) {
        int j = nb[t];
        const float* Uj = U + ((size_t)b * NP + j) * 12 + 6;
#pragma unroll
        for (int o = 0; o < 6; ++o) u2[o] += Uj[o];
    }
#pragma unroll
    for (int c = 0; c < 3; ++c)
#pragma unroll
        for (int s = 0; s < 2; ++s) {
            int o = c * 2 + s;
            float val = ALPHA_F * u1[o] + OMA_F * (0.125f * u2[o])
                      + xyz[(size_t)b * 3 * NP + (size_t)c * NP + n];
            out[(size_t)b * 3 * 2 * NP + (size_t)c * 2 * NP + (size_t)s * NP + n] = val;
        }
}

// ---------------------------------------------------------------------------
extern "C" void kernel_launch(void* const* d_in, const int* in_sizes, int n_in,
                              void* d_out, int out_size, void* d_ws, size_t ws_size,
                              hipStream_t stream) {
    const float* xyz    = (const float*)d_in[0];  // (16,3,2048)
    const float* points = (const float*)d_in[1];  // (16,128,2048)
    const float* Wc     = (const float*)d_in[2];  // (4,128,128)
    const float* Wg     = (const float*)d_in[3];  // (4,128,128)
    const float* Wuc    = (const float*)d_in[4];  // (6,128)
    const float* Wug    = (const float*)d_in[5];  // (6,128)
    float* out = (float*)d_out;

    char* ws = (char*)d_ws;
    size_t o = 0;
    int* nbr  = (int*)(ws + o);     o += (size_t)NB * NP * 7 * 4;
    uint4* WP = (uint4*)(ws + o);   o += (size_t)32768 * 16;           // 0.5 MB
    float* Za = (float*)(ws + o);   o += (size_t)NB * NP * NC * 4;     // 16 MB
    float* Ya = (float*)(ws + o);   o += (size_t)NB * NP * NC * 4;
    float* Zb = (float*)(ws + o);   o += (size_t)NB * NP * NC * 4;
    float* Yb = (float*)(ws + o);   o += (size_t)NB * NP * NC * 4;
    float* U  = (float*)(ws + o);   o += (size_t)NB * NP * 12 * 4;

    const int GEMM_GRID = NB * NP / 64;   // 512 tiles
    // WP slab bases: (layer*2 + mat) * 4096 uint4
    #define WPC(L) (WP + (size_t)((L) * 2 + 0) * 4096)
    #define WPG(L) (WP + (size_t)((L) * 2 + 1) * 4096)

    // 0) pre-split weights (one-time)
    prep_w_kernel<<<64, 256, 0, stream>>>(Wc, Wg, WP);
    // 1) KNN
    knn_kernel<<<dim3(NP / 64, NB), 256, 0, stream>>>(xyz, nbr);
    // 2) GCN blocks — agg fused into next block's A-staging
    gemm_fused_kernel<0><<<GEMM_GRID, 512, 0, stream>>>(points, nullptr, nullptr,
        WPC(0), WPG(0), Za, Ya);
    gemm_fused_kernel<1><<<GEMM_GRID, 512, 0, stream>>>(Za, Ya, nbr,
        WPC(1), WPG(1), Zb, Yb);
    gemm_fused_kernel<1><<<GEMM_GRID, 512, 0, stream>>>(Zb, Yb, nbr,
        WPC(2), WPG(2), Za, Ya);
    gemm_fused_kernel<1><<<GEMM_GRID, 512, 0, stream>>>(Za, Ya, nbr,
        WPC(3), WPG(3), Zb, Yb);
    // 3) last agg -> P5 (reuse Za)
    float* P5 = Za;
    agg_kernel<<<dim3(NB * NP / 8), 256, 0, stream>>>(Zb, Yb, nbr, P5);
    // 4) final small GEMMs
    final_gemm_kernel<<<dim3(NB * NP / 256), 256, 0, stream>>>(P5, Wuc, Wug, U);
    // 5) new_xyz
    final_out_kernel<<<dim3(NB * NP / 256), 256, 0, stream>>>(U, nbr, xyz, out);
    // 6) pts (B,N,C) -> out2 (B,C,N)
    transpose_kernel<<<dim3(NC / 32, NP / 32, NB), dim3(32, 8), 0, stream>>>(
        P5, out + (size_t)NB * 3 * 2 * NP, NP, NC);
}

// Round 11
// 225.596 us; speedup vs baseline: 5.9783x; 1.1439x over previous
//
#include <hip/hip_runtime.h>
#include <hip/hip_bf16.h>

// Problem constants
static constexpr int NB = 16;     // batches
static constexpr int NP = 2048;   // points per batch
static constexpr int NC = 128;    // channels
#define ALPHA_F ((float)(8.0/9.0))
#define OMA_F   ((float)(1.0 - 8.0/9.0))

typedef __attribute__((ext_vector_type(8))) short bfrag;   // 8 bf16 (4 VGPR)
typedef __attribute__((ext_vector_type(4))) float ffrag;   // 4 fp32 acc

union BU { bfrag v; uint4 u; unsigned int w[4]; };

// split two floats into packed bf16 hi pair + bf16 lo pair
__device__ inline void split2(float x, float y, unsigned& hi, unsigned& lo) {
    __hip_bfloat162 h = __float22bfloat162_rn(make_float2(x, y));
    float2 hb = __bfloat1622float2(h);
    __hip_bfloat162 l = __float22bfloat162_rn(make_float2(x - hb.x, y - hb.y));
    __builtin_memcpy(&hi, &h, 4);
    __builtin_memcpy(&lo, &l, 4);
}

__device__ inline void split1(float x, unsigned short& h, unsigned short& l) {
    __hip_bfloat16 hb = __float2bfloat16(x);
    float hf = __bfloat162float(hb);
    __hip_bfloat16 lb = __float2bfloat16(x - hf);
    __builtin_memcpy(&h, &hb, 2);
    __builtin_memcpy(&l, &lb, 2);
}

// ---------------------------------------------------------------------------
// KNN v4c (round-9, green): grouped two-phase scan via group bitmask.
// ---------------------------------------------------------------------------
__global__ __launch_bounds__(256) void knn_kernel(const float* __restrict__ xyz,
                                                  int* __restrict__ nbr) {
    __shared__ float4 sp[NP];            // 32 KB
    __shared__ float  md[64][33];
    __shared__ int    mi[64][33];
    int b = blockIdx.y;
    const float* X = xyz + (size_t)b * 3 * NP;
    for (int m = threadIdx.x; m < NP; m += 256) {
        float x = X[m], y = X[NP + m], z = X[2 * NP + m];
        sp[m] = make_float4(x, y, z, x * x + y * y + z * z);
    }
    __syncthreads();

    int tid = threadIdx.x;
    int p = tid >> 2;
    int q = tid & 3;
    int base = blockIdx.x * 64;
    int n = base + p;
    float4 me = sp[n];
    float xi = me.x, yi = me.y, zi = me.z, qi = me.w;

    // ---- pass 1: top-8 groups by group-min
    float gd[8]; int gi[8];
#pragma unroll
    for (int t = 0; t < 8; ++t) { gd[t] = 3.4e38f; gi[t] = 0; }
#pragma unroll 1
    for (int g = 0; g < 64; ++g) {
        float gm = 3.4e38f;
#pragma unroll
        for (int i = 0; i < 8; ++i) {
            int j = (g * 8 + i) * 4 + q;
            float4 c4v = sp[j];
            float inner = xi * c4v.x + yi * c4v.y + zi * c4v.z;
            float d = qi + c4v.w - 2.0f * inner;
            gm = fminf(gm, d);
        }
        bool c[8];
#pragma unroll
        for (int t = 0; t < 8; ++t) c[t] = gm < gd[t];
#pragma unroll
        for (int t = 7; t >= 1; --t) {
            gd[t] = c[t - 1] ? gd[t - 1] : (c[t] ? gm : gd[t]);
            gi[t] = c[t - 1] ? gi[t - 1] : (c[t] ? g : gi[t]);
        }
        gd[0] = c[0] ? gm : gd[0];
        gi[0] = c[0] ? g : gi[0];
    }

    unsigned long long mask = 0ull;
#pragma unroll
    for (int t = 0; t < 8; ++t) mask |= (1ull << gi[t]);

    // ---- pass 2: full insert over winning groups, ascending group order
    float bd[8]; int bi[8];
#pragma unroll
    for (int t = 0; t < 8; ++t) { bd[t] = 3.4e38f; bi[t] = 0; }
    while (mask) {
        int g = (int)__builtin_ctzll(mask);
        mask &= (mask - 1ull);
#pragma unroll
        for (int i = 0; i < 8; ++i) {
            int j = (g * 8 + i) * 4 + q;
            float4 c4v = sp[j];
            float inner = xi * c4v.x + yi * c4v.y + zi * c4v.z;
            float d = qi + c4v.w - 2.0f * inner;
            bool c[8];
#pragma unroll
            for (int t = 0; t < 8; ++t) c[t] = d < bd[t];
#pragma unroll
            for (int t = 7; t >= 1; --t) {
                bd[t] = c[t - 1] ? bd[t - 1] : (c[t] ? d : bd[t]);
                bi[t] = c[t - 1] ? bi[t - 1] : (c[t] ? j : bi[t]);
            }
            bd[0] = c[0] ? d : bd[0];
            bi[0] = c[0] ? j : bi[0];
        }
    }
#pragma unroll
    for (int t = 0; t < 8; ++t) {
        md[p][q * 8 + t] = bd[t];
        mi[p][q * 8 + t] = bi[t];
    }
    __syncthreads();

    if (tid < 64) {
        float fd[8]; int fi[8];
#pragma unroll
        for (int t = 0; t < 8; ++t) { fd[t] = 3.4e38f; fi[t] = 0; }
#pragma unroll 4
        for (int cc = 0; cc < 32; ++cc) {
            float d = md[tid][cc];
            int j = mi[tid][cc];
            bool c[8];
#pragma unroll
            for (int t = 0; t < 8; ++t) c[t] = d < fd[t];
#pragma unroll
            for (int t = 7; t >= 1; --t) {
                fd[t] = c[t - 1] ? fd[t - 1] : (c[t] ? d : fd[t]);
                fi[t] = c[t - 1] ? fi[t - 1] : (c[t] ? j : fi[t]);
            }
            fd[0] = c[0] ? d : fd[0];
            fi[0] = c[0] ? j : fi[0];
        }
        int row = b * NP + base + tid;
#pragma unroll
        for (int t = 0; t < 7; ++t) nbr[row * 7 + t] = fi[t + 1];
    }
}

// ---------------------------------------------------------------------------
// Generic batched transpose of last two dims: in (B,R,S) -> out (B,S,R)
// ---------------------------------------------------------------------------
__global__ __launch_bounds__(256) void transpose_kernel(const float* __restrict__ in,
                                                        float* __restrict__ out,
                                                        int R, int S) {
    __shared__ float t[32][33];
    int b = blockIdx.z;
    int s0 = blockIdx.x * 32, r0 = blockIdx.y * 32;
    const float* I = in + (size_t)b * R * S;
    float* O = out + (size_t)b * R * S;
#pragma unroll
    for (int i = 0; i < 4; ++i) {
        int r = r0 + threadIdx.y + i * 8;
        t[threadIdx.y + i * 8][threadIdx.x] = I[(size_t)r * S + s0 + threadIdx.x];
    }
    __syncthreads();
#pragma unroll
    for (int i = 0; i < 4; ++i) {
        int s = s0 + threadIdx.y + i * 8;
        O[(size_t)s * R + r0 + threadIdx.x] = t[threadIdx.x][threadIdx.y + i * 8];
    }
}

// ---------------------------------------------------------------------------
// Pre-split W into MFMA-frag-ordered bf16 hi/lo uint4 pairs (one-time).
// ---------------------------------------------------------------------------
__global__ __launch_bounds__(256) void prep_w_kernel(const float* __restrict__ Wc,
                                                     const float* __restrict__ Wg,
                                                     uint4* __restrict__ WP) {
    int t = blockIdx.x * 256 + threadIdx.x;
    int ncol = t & 127;
    int quad = (t >> 7) & 3;
    int s = (t >> 9) & 3;
    int mat = (t >> 11) & 1;
    int layer = t >> 12;
    const float* W = (mat ? Wg : Wc) + (size_t)layer * NC * NC + (size_t)ncol * NC + s * 32 + quad * 8;
    float4 a = *((const float4*)W);
    float4 b = *((const float4*)(W + 4));
    BU hi, lo;
    split2(a.x, a.y, hi.w[0], lo.w[0]);
    split2(a.z, a.w, hi.w[1], lo.w[1]);
    split2(b.x, b.y, hi.w[2], lo.w[2]);
    split2(b.z, b.w, hi.w[3], lo.w[3]);
    WP[t * 2] = hi.u;
    WP[t * 2 + 1] = lo.u;
}

// ---------------------------------------------------------------------------
// Fused GCN block v3 = v2 + XCD-aware block swizzle:
// blk -> (xcd = blk&7, slot = blk>>3); bb = xcd*2 + (slot>>5); tile = slot&31.
// With XCD = blockIdx%8 dispatch, each XCD owns exactly 2 batches, so the
// per-XCD L2 gather working set is 2 MB (fits 4 MB) instead of all 16 MB.
// Pure index permutation: bit-identical outputs.
// ---------------------------------------------------------------------------
template <int MODE>
__global__ __launch_bounds__(512) void gemm_fused_kernel(const float* __restrict__ Asrc,
                                                         const float* __restrict__ Y2in,
                                                         const int* __restrict__ nbr,
                                                         const uint4* __restrict__ WPc,
                                                         const uint4* __restrict__ WPg,
                                                         float* __restrict__ Zout,
                                                         float* __restrict__ Y2out) {
    __shared__ unsigned short AhT[64][136];   // 17.4 KB
    __shared__ unsigned short AlT[64][136];   // 17.4 KB
    __shared__ int s_nb[448];
    int tid = threadIdx.x;
    int wid = tid >> 6, lane = tid & 63;
    int quad = lane >> 4, l15 = lane & 15;
    int xcd = blockIdx.x & 7;
    int slot = blockIdx.x >> 3;
    int bb = xcd * 2 + (slot >> 5);           // batch
    int n0 = (slot & 31) << 6;                // tile base within batch
    size_t m0 = (size_t)bb * NP + n0;
    int ncol = wid * 16 + l15;

    // ---- W frags: pre-split, frag-ordered; 16 L2-hot b128 loads, zero VALU
    BU Bch[4], Bcl[4], Bgh[4], Bgl[4];
#pragma unroll
    for (int s = 0; s < 4; ++s) {
        int idx = ((s * 4 + quad) * 128 + ncol) * 2;
        Bch[s].u = WPc[idx];
        Bcl[s].u = WPc[idx + 1];
        Bgh[s].u = WPg[idx];
        Bgl[s].u = WPg[idx + 1];
    }

    // ---- stage A tile, splitting to bf16 planes inline
    if (MODE == 1) {
        if (tid < 448) s_nb[tid] = nbr[m0 * 7 + tid];
        __syncthreads();
        size_t bbase = (size_t)bb * NP;
#pragma unroll 1
        for (int it = 0; it < 4; ++it) {
            int f = tid + it * 512;
            int r = f >> 5, c4 = (f & 31) * 4;
            size_t row = m0 + r;
            float4 z = *((const float4*)(Asrc + row * NC + c4));
            float4 acc = *((const float4*)(Y2in + row * NC + c4));
#pragma unroll
            for (int t = 0; t < 7; ++t) {
                int j = s_nb[r * 7 + t];
                float4 v = *((const float4*)(Y2in + (bbase + (size_t)j) * NC + c4));
                acc.x += v.x; acc.y += v.y; acc.z += v.z; acc.w += v.w;
            }
            float4 a;
            a.x = OMA_F * (0.125f * acc.x) + z.x;
            a.y = OMA_F * (0.125f * acc.y) + z.y;
            a.z = OMA_F * (0.125f * acc.z) + z.z;
            a.w = OMA_F * (0.125f * acc.w) + z.w;
            unsigned h01, l01, h23, l23;
            split2(a.x, a.y, h01, l01);
            split2(a.z, a.w, h23, l23);
            *((uint2*)&AhT[r][c4]) = make_uint2(h01, h23);
            *((uint2*)&AlT[r][c4]) = make_uint2(l01, l23);
        }
    } else {
        // A[r][c] = points[b][c][n0+r]: float4 along n, split scalar, b16 writes
#pragma unroll
        for (int it = 0; it < 4; ++it) {
            int f = tid + it * 512;
            int c = f >> 4, rq = (f & 15) * 4;
            float4 v = *((const float4*)(Asrc + ((size_t)bb * NC + c) * NP + n0 + rq));
            float vv[4] = {v.x, v.y, v.z, v.w};
#pragma unroll
            for (int k = 0; k < 4; ++k) {
                unsigned short h, l;
                split1(vv[k], h, l);
                AhT[rq + k][c] = h;
                AlT[rq + k][c] = l;
            }
        }
    }
    __syncthreads();

    ffrag accC[4], accG[4];
#pragma unroll
    for (int mt = 0; mt < 4; ++mt) { accC[mt] = (ffrag)0.0f; accG[mt] = (ffrag)0.0f; }

#pragma unroll
    for (int s = 0; s < 4; ++s) {
#pragma unroll
        for (int mt = 0; mt < 4; ++mt) {
            int m = mt * 16 + l15;
            int k = s * 32 + quad * 8;
            BU ah, al, rh, rl;
            ah.u = *((const uint4*)&AhT[m][k]);
            al.u = *((const uint4*)&AlT[m][k]);
#pragma unroll
            for (int w = 0; w < 4; ++w) {
                unsigned msk = ((ah.w[w] & 0x80008000u) >> 15) * 0xFFFFu;
                rh.w[w] = ah.w[w] & ~msk;
                rl.w[w] = al.w[w] & ~msk;
            }
            accC[mt] = __builtin_amdgcn_mfma_f32_16x16x32_bf16(rh.v, Bch[s].v, accC[mt], 0, 0, 0);
            accC[mt] = __builtin_amdgcn_mfma_f32_16x16x32_bf16(rh.v, Bcl[s].v, accC[mt], 0, 0, 0);
            accC[mt] = __builtin_amdgcn_mfma_f32_16x16x32_bf16(rl.v, Bch[s].v, accC[mt], 0, 0, 0);
            accG[mt] = __builtin_amdgcn_mfma_f32_16x16x32_bf16(ah.v, Bgh[s].v, accG[mt], 0, 0, 0);
            accG[mt] = __builtin_amdgcn_mfma_f32_16x16x32_bf16(ah.v, Bgl[s].v, accG[mt], 0, 0, 0);
            accG[mt] = __builtin_amdgcn_mfma_f32_16x16x32_bf16(al.v, Bgh[s].v, accG[mt], 0, 0, 0);
        }
    }

    // ---- epilogue: col = l15, row = 4*quad + r; residual p = hi + lo
#pragma unroll
    for (int mt = 0; mt < 4; ++mt) {
        int rbase = mt * 16 + quad * 4;
#pragma unroll
        for (int r = 0; r < 4; ++r) {
            int rr = rbase + r;
            unsigned hb = ((unsigned)AhT[rr][ncol]) << 16;
            unsigned lb = ((unsigned)AlT[rr][ncol]) << 16;
            float hp, lp;
            __builtin_memcpy(&hp, &hb, 4);
            __builtin_memcpy(&lp, &lb, 4);
            float p = hp + lp;
            size_t idx = (m0 + rr) * NC + ncol;
            Zout[idx] = p + ALPHA_F * accC[mt][r];
            Y2out[idx] = accG[mt][r];
        }
    }
}

// ---------------------------------------------------------------------------
// Aggregate + XCD-aware swizzle (grid 4096, 256 blocks per batch):
// blk -> (xcd = blk&7, slot = blk>>3); bb = xcd*2 + (slot>>8); rblk = slot&255.
// ---------------------------------------------------------------------------
__global__ __launch_bounds__(256) void agg_kernel(const float* __restrict__ Z,
                                                  const float* __restrict__ Y2,
                                                  const int* __restrict__ nbr,
                                                  float* __restrict__ Pout) {
    int tid = threadIdx.x;
    int lane = tid & 31, rl = tid >> 5;
    int xcd = blockIdx.x & 7;
    int slot = blockIdx.x >> 3;
    int bb = xcd * 2 + (slot >> 8);
    int rblk = slot & 255;
    size_t row = ((size_t)bb << 11) + rblk * 8 + rl;
    const int* nb = nbr + row * 7;
    size_t off = row * NC + lane * 4;
    float4 ys = *((const float4*)(Y2 + off));
    size_t bbase = (size_t)bb * NP * NC;
#pragma unroll
    for (int t = 0; t < 7; ++t) {
        int j = nb[t];
        float4 v = *((const float4*)(Y2 + bbase + (size_t)j * NC + lane * 4));
        ys.x += v.x; ys.y += v.y; ys.z += v.z; ys.w += v.w;
    }
    float4 z = *((const float4*)(Z + off));
    float4 o;
    o.x = OMA_F * (0.125f * ys.x) + z.x;
    o.y = OMA_F * (0.125f * ys.y) + z.y;
    o.z = OMA_F * (0.125f * ys.z) + z.z;
    o.w = OMA_F * (0.125f * ys.w) + z.w;
    *((float4*)(Pout + off)) = o;
}

// ---------------------------------------------------------------------------
// Final small GEMMs: U1 = P @ Wuc^T (6), U2 = P @ Wug^T (6); U row = [U1|U2]
// ---------------------------------------------------------------------------
__global__ __launch_bounds__(256) void final_gemm_kernel(const float* __restrict__ P,
                                                         const float* __restrict__ Wuc,
                                                         const float* __restrict__ Wug,
                                                         float* __restrict__ U) {
    __shared__ float s1[6 * NC], s2[6 * NC];
    for (int m = threadIdx.x; m < 6 * NC; m += 256) { s1[m] = Wuc[m]; s2[m] = Wug[m]; }
    __syncthreads();
    size_t row = (size_t)blockIdx.x * 256 + threadIdx.x;
    const float4* prow = (const float4*)(P + row * NC);
    float a1[6] = {0, 0, 0, 0, 0, 0}, a2[6] = {0, 0, 0, 0, 0, 0};
#pragma unroll 4
    for (int c4 = 0; c4 < NC / 4; ++c4) {
        float4 p = prow[c4];
#pragma unroll
        for (int o = 0; o < 6; ++o) {
            float4 w1 = *((const float4*)&s1[o * NC + c4 * 4]);
            float4 w2 = *((const float4*)&s2[o * NC + c4 * 4]);
            a1[o] += p.x * w1.x + p.y * w1.y + p.z * w1.z + p.w * w1.w;
            a2[o] += p.x * w2.x + p.y * w2.y + p.z * w2.z + p.w * w2.w;
        }
    }
#pragma unroll
    for (int o = 0; o < 6; ++o) {
        U[row * 12 + o] = a1[o];
        U[row * 12 + 6 + o] = a2[o];
    }
}

// ---------------------------------------------------------------------------
// Final output: new_xyz
// ---------------------------------------------------------------------------
__global__ __launch_bounds__(256) void final_out_kernel(const float* __restrict__ U,
                                                        const int* __restrict__ nbr,
                                                        const float* __restrict__ xyz,
                                                        float* __restrict__ out) {
    size_t row = (size_t)blockIdx.x * 256 + threadIdx.x;
    int b = (int)(row >> 11), n = (int)(row & 2047);
    const int* nb = nbr + row * 7;
    float u1[6], u2[6];
#pragma unroll
    for (int o = 0; o < 6; ++o) { u1[o] = U[row * 12 + o]; u2[o] = U[row * 12 + 6 + o]; }
#pragma unroll
    for (int t = 0; t < 7; ++t) {
        int j = nb[t];
        const float* Uj = U + ((size_t)b * NP + j) * 12 + 6;
#pragma unroll
        for (int o = 0; o < 6; ++o) u2[o] += Uj[o];
    }
#pragma unroll
    for (int c = 0; c < 3; ++c)
#pragma unroll
        for (int s = 0; s < 2; ++s) {
            int o = c * 2 + s;
            float val = ALPHA_F * u1[o] + OMA_F * (0.125f * u2[o])
                      + xyz[(size_t)b * 3 * NP + (size_t)c * NP + n];
            out[(size_t)b * 3 * 2 * NP + (size_t)c * 2 * NP + (size_t)s * NP + n] = val;
        }
}

// ---------------------------------------------------------------------------
extern "C" void kernel_launch(void* const* d_in, const int* in_sizes, int n_in,
                              void* d_out, int out_size, void* d_ws, size_t ws_size,
                              hipStream_t stream) {
    const float* xyz    = (const float*)d_in[0];  // (16,3,2048)
    const float* points = (const float*)d_in[1];  // (16,128,2048)
    const float* Wc     = (const float*)d_in[2];  // (4,128,128)
    const float* Wg     = (const float*)d_in[3];  // (4,128,128)
    const float* Wuc    = (const float*)d_in[4];  // (6,128)
    const float* Wug    = (const float*)d_in[5];  // (6,128)
    float* out = (float*)d_out;

    char* ws = (char*)d_ws;
    size_t o = 0;
    int* nbr  = (int*)(ws + o);     o += (size_t)NB * NP * 7 * 4;
    uint4* WP = (uint4*)(ws + o);   o += (size_t)32768 * 16;           // 0.5 MB
    float* Za = (float*)(ws + o);   o += (size_t)NB * NP * NC * 4;     // 16 MB
    float* Ya = (float*)(ws + o);   o += (size_t)NB * NP * NC * 4;
    float* Zb = (float*)(ws + o);   o += (size_t)NB * NP * NC * 4;
    float* Yb = (float*)(ws + o);   o += (size_t)NB * NP * NC * 4;
    float* U  = (float*)(ws + o);   o += (size_t)NB * NP * 12 * 4;

    const int GEMM_GRID = NB * NP / 64;   // 512 tiles
    // WP slab bases: (layer*2 + mat) * 4096 uint4
    #define WPC(L) (WP + (size_t)((L) * 2 + 0) * 4096)
    #define WPG(L) (WP + (size_t)((L) * 2 + 1) * 4096)

    // 0) pre-split weights (one-time)
    prep_w_kernel<<<64, 256, 0, stream>>>(Wc, Wg, WP);
    // 1) KNN
    knn_kernel<<<dim3(NP / 64, NB), 256, 0, stream>>>(xyz, nbr);
    // 2) GCN blocks — agg fused into next block's A-staging
    gemm_fused_kernel<0><<<GEMM_GRID, 512, 0, stream>>>(points, nullptr, nullptr,
        WPC(0), WPG(0), Za, Ya);
    gemm_fused_kernel<1><<<GEMM_GRID, 512, 0, stream>>>(Za, Ya, nbr,
        WPC(1), WPG(1), Zb, Yb);
    gemm_fused_kernel<1><<<GEMM_GRID, 512, 0, stream>>>(Zb, Yb, nbr,
        WPC(2), WPG(2), Za, Ya);
    gemm_fused_kernel<1><<<GEMM_GRID, 512, 0, stream>>>(Za, Ya, nbr,
        WPC(3), WPG(3), Zb, Yb);
    // 3) last agg -> P5 (reuse Za)
    float* P5 = Za;
    agg_kernel<<<dim3(NB * NP / 8), 256, 0, stream>>>(Zb, Yb, nbr, P5);
    // 4) final small GEMMs
    final_gemm_kernel<<<dim3(NB * NP / 256), 256, 0, stream>>>(P5, Wuc, Wug, U);
    // 5) new_xyz
    final_out_kernel<<<dim3(NB * NP / 256), 256, 0, stream>>>(U, nbr, xyz, out);
    // 6) pts (B,N,C) -> out2 (B,C,N)
    transpose_kernel<<<dim3(NC / 32, NP / 32, NB), dim3(32, 8), 0, stream>>>(
        P5, out + (size_t)NB * 3 * 2 * NP, NP, NC);
}